// Round 4
// baseline (1181.763 us; speedup 1.0000x reference)
//
#include <hip/hip_runtime.h>
#include <cstdint>
#include <cstddef>

typedef unsigned short u16;
typedef __bf16 bf16x8 __attribute__((ext_vector_type(8)));
typedef float f32x4 __attribute__((ext_vector_type(4)));

#define N_NODES 20000
#define MPAD    20096      // 157 * 128
#define E_EDGES 640000
#define K1      3000
#define K1P     3008       // 47 * 64
#define H_DIM   512
#define NW      1024       // W1|W2 fused width
#define O_DIM   256

__device__ __forceinline__ float bf2f(unsigned int hi) {
  union { unsigned int u; float f; } v; v.u = hi << 16; return v.f;
}
__device__ __forceinline__ u16 f2bf(float f) {
  union { float f; unsigned int u; } v; v.f = f;
  unsigned int u = v.u;
  return (u16)((u + 0x7fffu + ((u >> 16) & 1u)) >> 16);
}

__device__ __forceinline__ void gl2lds16(const void* g, void* l) {
  __builtin_amdgcn_global_load_lds((const __attribute__((address_space(1))) void*)g,
                                   (__attribute__((address_space(3))) void*)l, 16, 0, 0);
}

// ---------------- edge preprocessing ----------------
__global__ __launch_bounds__(256) void deg_init_k(float* degS, float* degD, int* cntS, int* cntD) {
  int i = blockIdx.x * 256 + threadIdx.x;
  if (i < N_NODES) { degS[i] = 1.0f; degD[i] = 1.0f; cntS[i] = 0; cntD[i] = 0; }
}

__global__ __launch_bounds__(256) void deg_accum_k(const int* eiS, const float* ewS,
                                                   const int* eiD, const float* ewD,
                                                   float* degS, float* degD, int* cntS, int* cntD) {
  int e = blockIdx.x * 256 + threadIdx.x;
  if (e < E_EDGES) {
    int cs = eiS[E_EDGES + e];
    atomicAdd(&degS[cs], ewS[e]);
    atomicAdd(&cntS[cs], 1);
    int cd = eiD[E_EDGES + e];
    atomicAdd(&degD[cd], ewD[e]);
    atomicAdd(&cntD[cd], 1);
  }
}

__global__ __launch_bounds__(256) void dinv_k(const float* degS, const float* degD,
                                              float* dinvS, float* dinvD) {
  int i = blockIdx.x * 256 + threadIdx.x;
  if (i < N_NODES) { dinvS[i] = rsqrtf(degS[i]); dinvD[i] = rsqrtf(degD[i]); }
}

__global__ __launch_bounds__(1024) void scan_k(const int* cntS, int* offS, int* curS,
                                               const int* cntD, int* offD, int* curD) {
  const int* cnt = blockIdx.x ? cntD : cntS;
  int* off = blockIdx.x ? offD : offS;
  int* cur = blockIdx.x ? curD : curS;
  __shared__ int sums[1024];
  const int t = threadIdx.x;
  const int CH = 20;
  int base = t * CH;
  int s = 0;
  for (int j = 0; j < CH; ++j) { int idx = base + j; if (idx < N_NODES) s += cnt[idx]; }
  sums[t] = s;
  __syncthreads();
  for (int d = 1; d < 1024; d <<= 1) {
    int v = (t >= d) ? sums[t - d] : 0;
    __syncthreads();
    sums[t] += v;
    __syncthreads();
  }
  int run = sums[t] - s;   // exclusive prefix
  for (int j = 0; j < CH; ++j) {
    int idx = base + j;
    if (idx <= N_NODES) {
      off[idx] = run; cur[idx] = run;
      if (idx < N_NODES) run += cnt[idx];
    }
  }
}

__global__ __launch_bounds__(256) void scatter_k(const int* eiS, const float* ewS, const float* dinvS,
                                                 int* curS, int* ssrcS, float* snrmS,
                                                 const int* eiD, const float* ewD, const float* dinvD,
                                                 int* curD, int* ssrcD, float* snrmD) {
  int e = blockIdx.x * 256 + threadIdx.x;
  if (e < E_EDGES) {
    {
      int r = eiS[e], c = eiS[E_EDGES + e];
      int pos = atomicAdd(&curS[c], 1);
      ssrcS[pos] = r;
      snrmS[pos] = dinvS[r] * ewS[e] * dinvS[c];
    }
    {
      int r = eiD[e], c = eiD[E_EDGES + e];
      int pos = atomicAdd(&curD[c], 1);
      ssrcD[pos] = r;
      snrmD[pos] = dinvD[r] * ewD[e] * dinvD[c];
    }
  }
}

// ---------------- weight conversions ----------------
// W1,W2 [3000][512] -> w12t [1024][3008] bf16 (transposed, padded), LDS-tiled 64x64
__global__ __launch_bounds__(256) void conv_w12_k(const float* __restrict__ W1,
                                                  const float* __restrict__ W2,
                                                  u16* __restrict__ w12t) {
  __shared__ float t[64][65];
  const int kb = blockIdx.x;           // 0..46
  const int nb = blockIdx.y;           // 0..15
  const int n0 = nb * 64;
  const float* W = (n0 < H_DIM) ? W1 : W2;
  const int nn0 = n0 & (H_DIM - 1);
  const int k0 = kb * 64;
  const int tc = threadIdx.x & 63;
  const int tr4 = threadIdx.x >> 6;    // 0..3
#pragma unroll
  for (int rr = 0; rr < 16; ++rr) {
    int r = tr4 * 16 + rr;
    int k = k0 + r;
    t[r][tc] = (k < K1) ? W[(size_t)k * H_DIM + nn0 + tc] : 0.f;
  }
  __syncthreads();
#pragma unroll
  for (int rr = 0; rr < 16; ++rr) {
    int n = tr4 * 16 + rr;
    w12t[(size_t)(n0 + n) * K1P + k0 + tc] = f2bf(t[tc][n]);
  }
}

// Ws/Wd/Wf [512][256] -> [256][512] bf16, LDS-tiled 64x64
__global__ __launch_bounds__(256) void conv_wsm_k(const float* Ws, const float* Wd, const float* Wf,
                                                  u16* wst, u16* wdt, u16* wft) {
  __shared__ float t[64][65];
  const int which = blockIdx.z;
  const float* W = (which == 0) ? Ws : (which == 1) ? Wd : Wf;
  u16* o = (which == 0) ? wst : (which == 1) ? wdt : wft;
  const int k0 = blockIdx.x * 64;      // 0..448
  const int n0 = blockIdx.y * 64;      // 0..192
  const int tc = threadIdx.x & 63;
  const int tr4 = threadIdx.x >> 6;
#pragma unroll
  for (int rr = 0; rr < 16; ++rr) {
    int r = tr4 * 16 + rr;
    t[r][tc] = W[(size_t)(k0 + r) * O_DIM + n0 + tc];
  }
  __syncthreads();
#pragma unroll
  for (int rr = 0; rr < 16; ++rr) {
    int n = tr4 * 16 + rr;
    o[(size_t)(n0 + n) * H_DIM + k0 + tc] = f2bf(t[tc][n]);
  }
}

// ---------------- shared GEMM body: C[M,N] = A[M,K] * Bt[N,K]^T (bf16 in, fp32 acc) --------
// LDS layout: row-major [128][64] u16 with XOR granule swizzle: physical 16B-granule p of
// row r holds logical granule p ^ (r&7).  Staging picks global granule (tid&7)^((tid>>3)&7)
// so the wave-uniform global_load_lds dest (base + lane*16B) lands each granule at its
// swizzled position.  Fragment ds_read_b128 then hits 8 distinct bank-quads per 8-lane
// phase group -> conflict-free (measured 0 SQ_LDS_BANK_CONFLICT).
template <typename CT, bool BIAS>
__device__ __forceinline__ void gemm_body(const u16* __restrict__ A, const u16* __restrict__ Bt,
                                          CT* __restrict__ C, const float* __restrict__ bias,
                                          int Mreal, int K, int ldc) {
  __shared__ alignas(16) u16 As[128 * 64];
  __shared__ alignas(16) u16 Bs[128 * 64];
  const int tid = threadIdx.x;
  const int lane = tid & 63;
  const int wv = tid >> 6;
  const int bm = blockIdx.y * 128;
  const int bn = blockIdx.x * 128;

  const int wm = (wv >> 1) << 6;
  const int wn = (wv & 1) << 6;
  const int frow = lane & 15;
  const int q = lane >> 4;             // logical granule base (0..3)
  const int r7 = lane & 7;             // row&7 for all fragment rows this lane touches

  const int srow = tid >> 3;           // 0..31
  const int sgr = ((tid & 7) ^ ((tid >> 3) & 7)) << 3;   // swizzled granule * 8 u16
  const u16* ga = A + (size_t)(bm + srow) * K + sgr;
  const u16* gb = Bt + (size_t)(bn + srow) * K + sgr;
  u16* la = &As[wv * 512];
  u16* lb = &Bs[wv * 512];

  f32x4 acc[4][4] = {};

  for (int k0 = 0; k0 < K; k0 += 64) {
#pragma unroll
    for (int r = 0; r < 4; ++r) {
      gl2lds16(ga + (size_t)(r * 32) * K + k0, la + r * 2048);
      gl2lds16(gb + (size_t)(r * 32) * K + k0, lb + r * 2048);
    }
    __syncthreads();
#pragma unroll
    for (int ks = 0; ks < 64; ks += 32) {
      const int p = (((q + (ks >> 3)) ^ r7) << 3);   // physical u16 offset within row
      bf16x8 af[4], bv[4];
#pragma unroll
      for (int t = 0; t < 4; ++t) {
        af[t] = *(const bf16x8*)&As[(wm + t * 16 + frow) * 64 + p];
        bv[t] = *(const bf16x8*)&Bs[(wn + t * 16 + frow) * 64 + p];
      }
#pragma unroll
      for (int i = 0; i < 4; ++i)
#pragma unroll
        for (int j = 0; j < 4; ++j)
          acc[i][j] = __builtin_amdgcn_mfma_f32_16x16x32_bf16(af[i], bv[j], acc[i][j], 0, 0, 0);
    }
    __syncthreads();
  }

  // C/D layout (m89-verified): col = lane&15, row = (lane>>4)*4 + reg
  const int crow = (lane >> 4) << 2;
  const int ccol = lane & 15;
#pragma unroll
  for (int i = 0; i < 4; ++i) {
#pragma unroll
    for (int r = 0; r < 4; ++r) {
      int gr = bm + wm + i * 16 + crow + r;
      if (gr < Mreal) {
#pragma unroll
        for (int j = 0; j < 4; ++j) {
          int gc = bn + wn + j * 16 + ccol;
          float v = acc[i][j][r];
          if constexpr (BIAS) v += bias[gc];
          if constexpr (sizeof(CT) == 2) C[(size_t)gr * ldc + gc] = (CT)f2bf(v);
          else C[(size_t)gr * ldc + gc] = (CT)v;
        }
      }
    }
  }
}

// middle pair: hsb = xs@Ws^T, hdb = xd@Wd^T in one dispatch (z selects), grid (2,157,2)
__global__ __launch_bounds__(256) void gemm_pair_k(const u16* A0, const u16* B0, u16* C0,
                                                   const u16* A1, const u16* B1, u16* C1) {
  const u16* A = blockIdx.z ? A1 : A0;
  const u16* Bt = blockIdx.z ? B1 : B0;
  u16* C = blockIdx.z ? C1 : C0;
  gemm_body<u16, false>(A, Bt, C, nullptr, N_NODES, H_DIM, O_DIM);
}

// final: fused = xcat @ wft^T + bf (float out)
__global__ __launch_bounds__(256) void gemm_f_k(const u16* A, const u16* Bt, float* C,
                                                const float* bias) {
  gemm_body<float, true>(A, Bt, C, bias, N_NODES, H_DIM, O_DIM);
}

// ---------------- fused big GEMM: h12 = bf16(x) @ w12t^T ----------------
// A (x, f32 [20000][3000]) is reg-staged (conv_x folded in).  v2: T14 async-STAGE split +
// full double-buffer (As[2]/Bs[2], 64KB) with ONE barrier per K-step:
//   iter t: issue A f32 loads for t+1 (first, so their implicit waitcnt leaves B in flight)
//           issue B global_load_lds for t+1 into buf^1
//           MFMA on buf          <- the issue->use window that hides A-load latency
//           cvt + ds_write A(t+1) into buf^1   (compiler inserts the vmcnt wait here)
//           __syncthreads()      <- vmcnt(0) drain doubles as the B-DMA fence
// Double-buffering makes the second barrier unnecessary: writes to buf^1 at t are ordered
// after all reads of buf^1 (= cur of t-1) by barrier t-1.
// K-tail fix: at the last tile, lanes with lgr==7 would read cols 3000..3007 (past row end,
// garbage/OOB for row 19999); redirect them to col-block 0 (finite) -- B is zero there, so
// the product contributes 0 regardless.
__global__ __launch_bounds__(256) void gemm_x_k(const float* __restrict__ X,
                                                const u16* __restrict__ Bt,
                                                u16* __restrict__ C) {
  __shared__ alignas(16) u16 As[2][128 * 64];
  __shared__ alignas(16) u16 Bs[2][128 * 64];
  const int tid = threadIdx.x;
  const int lane = tid & 63;
  const int wv = tid >> 6;

  // XCD chunk swizzle (nwg = 8*157 = 1256, %8 == 0): each XCD gets a contiguous M-chunk
  // across all 8 N-blocks -> A-panel reuse is L2-local (measured FETCH 478->119 MB bf16).
  const int h = blockIdx.y * 8 + blockIdx.x;
  const int chunk = 157;               // 1256 / 8
  const int L = (h & 7) * chunk + (h >> 3);
  const int bn = (L & 7) * 128;
  const int bm = (L >> 3) * 128;

  const int wm = (wv >> 1) << 6;
  const int wn = (wv & 1) << 6;
  const int frow = lane & 15;
  const int q = lane >> 4;
  const int r7 = lane & 7;

  const int srow = tid >> 3;                       // 0..31
  const int lgr = (tid & 7) ^ (srow & 7);          // logical granule (8 cols)
  const float* xa[4];
#pragma unroll
  for (int r = 0; r < 4; ++r) {
    int row = bm + srow + r * 32;
    if (row >= N_NODES) row = 0;                   // discarded rows -> safe source
    xa[r] = X + (size_t)row * K1 + lgr * 8;
  }
  const u16* gb = Bt + (size_t)(bn + srow) * K1P + (lgr << 3);

  f32x4 acc[4][4] = {};
  constexpr int NT = K1P / 64;                     // 47

  // ---- prologue: stage tile 0 into buffer 0 (no hiding; one-time) ----
  {
    float4 a0[4], a1[4];
#pragma unroll
    for (int r = 0; r < 4; ++r) {
      a0[r] = *(const float4*)(xa[r]);
      a1[r] = *(const float4*)(xa[r] + 4);
    }
#pragma unroll
    for (int r = 0; r < 4; ++r)
      gl2lds16(gb + (size_t)(r * 32) * K1P, &Bs[0][wv * 512] + r * 2048);
#pragma unroll
    for (int r = 0; r < 4; ++r) {
      bf16x8 pk;
      pk[0] = (__bf16)a0[r].x; pk[1] = (__bf16)a0[r].y; pk[2] = (__bf16)a0[r].z; pk[3] = (__bf16)a0[r].w;
      pk[4] = (__bf16)a1[r].x; pk[5] = (__bf16)a1[r].y; pk[6] = (__bf16)a1[r].z; pk[7] = (__bf16)a1[r].w;
      *(bf16x8*)&As[0][r * 2048 + tid * 8] = pk;
    }
    __syncthreads();
  }

  int cur = 0;
  for (int t = 0; t < NT; ++t) {
    const int nxt = cur ^ 1;
    float4 a0[4], a1[4];
    const bool pf = (t + 1 < NT);
    if (pf) {
      int k0n = (t + 1) * 64;
      if (k0n + (lgr << 3) >= K1) k0n = 0;         // K-tail lanes -> finite data x B==0
#pragma unroll
      for (int r = 0; r < 4; ++r) {
        a0[r] = *(const float4*)(xa[r] + k0n);
        a1[r] = *(const float4*)(xa[r] + k0n + 4);
      }
      const int k0b = (t + 1) * 64;
#pragma unroll
      for (int r = 0; r < 4; ++r)
        gl2lds16(gb + (size_t)(r * 32) * K1P + k0b, &Bs[nxt][wv * 512] + r * 2048);
    }
    // compute on buffer cur
#pragma unroll
    for (int ks = 0; ks < 64; ks += 32) {
      const int p = (((q + (ks >> 3)) ^ r7) << 3);
      bf16x8 af[4], bv[4];
#pragma unroll
      for (int u = 0; u < 4; ++u) {
        af[u] = *(const bf16x8*)&As[cur][(wm + u * 16 + frow) * 64 + p];
        bv[u] = *(const bf16x8*)&Bs[cur][(wn + u * 16 + frow) * 64 + p];
      }
#pragma unroll
      for (int i = 0; i < 4; ++i)
#pragma unroll
        for (int j = 0; j < 4; ++j)
          acc[i][j] = __builtin_amdgcn_mfma_f32_16x16x32_bf16(af[i], bv[j], acc[i][j], 0, 0, 0);
    }
    if (pf) {
#pragma unroll
      for (int r = 0; r < 4; ++r) {
        bf16x8 pk;
        pk[0] = (__bf16)a0[r].x; pk[1] = (__bf16)a0[r].y; pk[2] = (__bf16)a0[r].z; pk[3] = (__bf16)a0[r].w;
        pk[4] = (__bf16)a1[r].x; pk[5] = (__bf16)a1[r].y; pk[6] = (__bf16)a1[r].z; pk[7] = (__bf16)a1[r].w;
        *(bf16x8*)&As[nxt][r * 2048 + tid * 8] = pk;
      }
    }
    __syncthreads();
    cur = nxt;
  }

  const int crow = (lane >> 4) << 2;
  const int ccol = lane & 15;
#pragma unroll
  for (int i = 0; i < 4; ++i) {
#pragma unroll
    for (int r = 0; r < 4; ++r) {
      int gr = bm + wm + i * 16 + crow + r;
      if (gr < N_NODES) {
#pragma unroll
        for (int j = 0; j < 4; ++j) {
          int gc = bn + wn + j * 16 + ccol;
          C[(size_t)gr * NW + gc] = f2bf(acc[i][j][r]);
        }
      }
    }
  }
}

// ---------------- aggregation layer 1 ----------------
// Edge loop unrolled x4: batch the src/nrm loads, then issue all 4 row-gathers
// back-to-back before consuming -> ~4x the in-flight VMEM per wave (latency-bound fix).
__global__ __launch_bounds__(256) void agg1_k(const u16* __restrict__ h12,
                                              const int* offS, const int* srcS, const float* nrmS,
                                              const float* dinvS, const float* b1,
                                              const int* offD, const int* srcD, const float* nrmD,
                                              const float* dinvD, const float* b2,
                                              u16* __restrict__ xsd) {
  const int lane = threadIdx.x & 63;
  const int wv = threadIdx.x >> 6;
  const int i = blockIdx.x * 4 + wv;       // node (0..MPAD)
  const int g = blockIdx.y;
  if (i >= MPAD) return;
  u16* outp = xsd + ((size_t)g * MPAD + i) * H_DIM + lane * 8;
  if (i >= N_NODES) { uint4 z = {0, 0, 0, 0}; *(uint4*)outp = z; return; }

  const int* off = g ? offD : offS;
  const int* src = g ? srcD : srcS;
  const float* nrm = g ? nrmD : nrmS;
  const float* dinv = g ? dinvD : dinvS;
  const float* bias = g ? b2 : b1;
  const u16* hb = h12 + (size_t)g * H_DIM + lane * 8;

  float a[8];
  float dv = dinv[i];
  float sw = dv * dv;
  uint4 u = *(const uint4*)(hb + (size_t)i * NW);
  a[0] = sw * bf2f(u.x & 0xffff); a[1] = sw * bf2f(u.x >> 16);
  a[2] = sw * bf2f(u.y & 0xffff); a[3] = sw * bf2f(u.y >> 16);
  a[4] = sw * bf2f(u.z & 0xffff); a[5] = sw * bf2f(u.z >> 16);
  a[6] = sw * bf2f(u.w & 0xffff); a[7] = sw * bf2f(u.w >> 16);

  const int e0 = off[i], e1 = off[i + 1];
  int e = e0;
  for (; e + 4 <= e1; e += 4) {
    int ss[4]; float ww[4];
#pragma unroll
    for (int t = 0; t < 4; ++t) { ss[t] = src[e + t]; ww[t] = nrm[e + t]; }
    uint4 vv[4];
#pragma unroll
    for (int t = 0; t < 4; ++t) vv[t] = *(const uint4*)(hb + (size_t)ss[t] * NW);
#pragma unroll
    for (int t = 0; t < 4; ++t) {
      float w = ww[t]; uint4 v = vv[t];
      a[0] += w * bf2f(v.x & 0xffff); a[1] += w * bf2f(v.x >> 16);
      a[2] += w * bf2f(v.y & 0xffff); a[3] += w * bf2f(v.y >> 16);
      a[4] += w * bf2f(v.z & 0xffff); a[5] += w * bf2f(v.z >> 16);
      a[6] += w * bf2f(v.w & 0xffff); a[7] += w * bf2f(v.w >> 16);
    }
  }
  for (; e < e1; ++e) {
    int s = src[e];
    float w = nrm[e];
    uint4 v = *(const uint4*)(hb + (size_t)s * NW);
    a[0] += w * bf2f(v.x & 0xffff); a[1] += w * bf2f(v.x >> 16);
    a[2] += w * bf2f(v.y & 0xffff); a[3] += w * bf2f(v.y >> 16);
    a[4] += w * bf2f(v.z & 0xffff); a[5] += w * bf2f(v.z >> 16);
    a[6] += w * bf2f(v.w & 0xffff); a[7] += w * bf2f(v.w >> 16);
  }
  float4 bA = *(const float4*)(bias + lane * 8);
  float4 bB = *(const float4*)(bias + lane * 8 + 4);
  a[0] = fmaxf(a[0] + bA.x, 0.f); a[1] = fmaxf(a[1] + bA.y, 0.f);
  a[2] = fmaxf(a[2] + bA.z, 0.f); a[3] = fmaxf(a[3] + bA.w, 0.f);
  a[4] = fmaxf(a[4] + bB.x, 0.f); a[5] = fmaxf(a[5] + bB.y, 0.f);
  a[6] = fmaxf(a[6] + bB.z, 0.f); a[7] = fmaxf(a[7] + bB.w, 0.f);
  uint4 o;
  o.x = f2bf(a[0]) | ((unsigned)f2bf(a[1]) << 16);
  o.y = f2bf(a[2]) | ((unsigned)f2bf(a[3]) << 16);
  o.z = f2bf(a[4]) | ((unsigned)f2bf(a[5]) << 16);
  o.w = f2bf(a[6]) | ((unsigned)f2bf(a[7]) << 16);
  *(uint4*)outp = o;
}

// ---------------- aggregation layer 2 ----------------
__global__ __launch_bounds__(256) void agg2_k(const u16* __restrict__ hsb, const u16* __restrict__ hdb,
                                              const int* offS, const int* srcS, const float* nrmS,
                                              const float* dinvS, const float* bs,
                                              const int* offD, const int* srcD, const float* nrmD,
                                              const float* dinvD, const float* bd,
                                              float* __restrict__ outF, u16* __restrict__ xcat) {
  const int lane = threadIdx.x & 63;
  const int wv = threadIdx.x >> 6;
  const int i = blockIdx.x * 4 + wv;
  const int g = blockIdx.y;
  if (i >= MPAD) return;
  u16* oc = xcat + (size_t)i * H_DIM + (size_t)g * O_DIM + lane * 4;
  if (i >= N_NODES) { uint2 z = {0, 0}; *(uint2*)oc = z; return; }

  const u16* h = g ? hdb : hsb;
  const int* off = g ? offD : offS;
  const int* src = g ? srcD : srcS;
  const float* nrm = g ? nrmD : nrmS;
  const float* dinv = g ? dinvD : dinvS;
  const float* bias = g ? bd : bs;
  const u16* hb = h + lane * 4;

  float a[4];
  float dv = dinv[i];
  float sw = dv * dv;
  uint2 u = *(const uint2*)(hb + (size_t)i * O_DIM);
  a[0] = sw * bf2f(u.x & 0xffff); a[1] = sw * bf2f(u.x >> 16);
  a[2] = sw * bf2f(u.y & 0xffff); a[3] = sw * bf2f(u.y >> 16);

  const int e0 = off[i], e1 = off[i + 1];
  int e = e0;
  for (; e + 8 <= e1; e += 8) {
    int ss[8]; float ww[8];
#pragma unroll
    for (int t = 0; t < 8; ++t) { ss[t] = src[e + t]; ww[t] = nrm[e + t]; }
    uint2 vv[8];
#pragma unroll
    for (int t = 0; t < 8; ++t) vv[t] = *(const uint2*)(hb + (size_t)ss[t] * O_DIM);
#pragma unroll
    for (int t = 0; t < 8; ++t) {
      float w = ww[t]; uint2 v = vv[t];
      a[0] += w * bf2f(v.x & 0xffff); a[1] += w * bf2f(v.x >> 16);
      a[2] += w * bf2f(v.y & 0xffff); a[3] += w * bf2f(v.y >> 16);
    }
  }
  for (; e < e1; ++e) {
    int s = src[e];
    float w = nrm[e];
    uint2 v = *(const uint2*)(hb + (size_t)s * O_DIM);
    a[0] += w * bf2f(v.x & 0xffff); a[1] += w * bf2f(v.x >> 16);
    a[2] += w * bf2f(v.y & 0xffff); a[3] += w * bf2f(v.y >> 16);
  }
  float4 bb = *(const float4*)(bias + lane * 4);
  a[0] += bb.x; a[1] += bb.y; a[2] += bb.z; a[3] += bb.w;

  float4 fo = {a[0], a[1], a[2], a[3]};
  *(float4*)(outF + (size_t)g * N_NODES * O_DIM + (size_t)i * O_DIM + lane * 4) = fo;
  uint2 o;
  o.x = f2bf(a[0]) | ((unsigned)f2bf(a[1]) << 16);
  o.y = f2bf(a[2]) | ((unsigned)f2bf(a[3]) << 16);
  *(uint2*)oc = o;
}

// ---------------- launch ----------------
extern "C" void kernel_launch(void* const* d_in, const int* in_sizes, int n_in,
                              void* d_out, int out_size, void* d_ws, size_t ws_size,
                              hipStream_t stream) {
  const float* x = (const float*)d_in[0];
  const int* eiS = (const int*)d_in[1];
  const float* ewS = (const float*)d_in[2];
  const int* eiD = (const int*)d_in[3];
  const float* ewD = (const float*)d_in[4];
  const float* W1 = (const float*)d_in[5];
  const float* b1 = (const float*)d_in[6];
  const float* W2 = (const float*)d_in[7];
  const float* b2 = (const float*)d_in[8];
  const float* Ws = (const float*)d_in[9];
  const float* bs = (const float*)d_in[10];
  const float* Wd = (const float*)d_in[11];
  const float* bd = (const float*)d_in[12];
  const float* Wf = (const float*)d_in[13];
  const float* bf_ = (const float*)d_in[14];
  float* out = (float*)d_out;

  char* p = (char*)d_ws;
  auto alloc = [&](size_t n) -> char* { char* r = p; p += (n + 255) & ~(size_t)255; return r; };

  u16* w12t  = (u16*)alloc((size_t)NW * K1P * 2);
  u16* h12   = (u16*)alloc((size_t)N_NODES * NW * 2);
  u16* xsd   = (u16*)alloc((size_t)2 * MPAD * H_DIM * 2);
  u16* hsb   = (u16*)alloc((size_t)N_NODES * O_DIM * 2);
  u16* hdb   = (u16*)alloc((size_t)N_NODES * O_DIM * 2);
  u16* xcat  = (u16*)alloc((size_t)MPAD * H_DIM * 2);
  u16* wst   = (u16*)alloc((size_t)O_DIM * H_DIM * 2);
  u16* wdt   = (u16*)alloc((size_t)O_DIM * H_DIM * 2);
  u16* wft   = (u16*)alloc((size_t)O_DIM * H_DIM * 2);
  float* degS = (float*)alloc((size_t)N_NODES * 4);
  float* degD = (float*)alloc((size_t)N_NODES * 4);
  float* dinvS = (float*)alloc((size_t)N_NODES * 4);
  float* dinvD = (float*)alloc((size_t)N_NODES * 4);
  int* cntS = (int*)alloc((size_t)N_NODES * 4);
  int* cntD = (int*)alloc((size_t)N_NODES * 4);
  int* offS = (int*)alloc((size_t)(N_NODES + 1) * 4);
  int* offD = (int*)alloc((size_t)(N_NODES + 1) * 4);
  int* curS = (int*)alloc((size_t)(N_NODES + 1) * 4);
  int* curD = (int*)alloc((size_t)(N_NODES + 1) * 4);
  int* ssrcS = (int*)alloc((size_t)E_EDGES * 4);
  int* ssrcD = (int*)alloc((size_t)E_EDGES * 4);
  float* snrmS = (float*)alloc((size_t)E_EDGES * 4);
  float* snrmD = (float*)alloc((size_t)E_EDGES * 4);

  const int gN = (N_NODES + 255) / 256;     // 79
  const int gE = (E_EDGES + 255) / 256;     // 2500

  deg_init_k<<<gN, 256, 0, stream>>>(degS, degD, cntS, cntD);
  deg_accum_k<<<gE, 256, 0, stream>>>(eiS, ewS, eiD, ewD, degS, degD, cntS, cntD);
  dinv_k<<<gN, 256, 0, stream>>>(degS, degD, dinvS, dinvD);
  scan_k<<<2, 1024, 0, stream>>>(cntS, offS, curS, cntD, offD, curD);
  scatter_k<<<gE, 256, 0, stream>>>(eiS, ewS, dinvS, curS, ssrcS, snrmS,
                                    eiD, ewD, dinvD, curD, ssrcD, snrmD);

  conv_w12_k<<<dim3(47, 16), 256, 0, stream>>>(W1, W2, w12t);
  conv_wsm_k<<<dim3(8, 4, 3), 256, 0, stream>>>(Ws, Wd, Wf, wst, wdt, wft);

  // h12 = bf16(x) @ w12t^T  [20000 x 1024], conv_x fused, double-buffered + prefetched
  gemm_x_k<<<dim3(8, 157), 256, 0, stream>>>(x, w12t, h12);

  agg1_k<<<dim3(MPAD / 4, 2), 256, 0, stream>>>(h12, offS, ssrcS, snrmS, dinvS, b1,
                                                offD, ssrcD, snrmD, dinvD, b2, xsd);

  // hsb = xs @ Ws^T and hdb = xd @ Wd^T in one dispatch (628 blocks)
  gemm_pair_k<<<dim3(2, 157, 2), 256, 0, stream>>>(xsd, wst, hsb,
                                                   xsd + (size_t)MPAD * H_DIM, wdt, hdb);

  agg2_k<<<dim3(MPAD / 4, 2), 256, 0, stream>>>(hsb, hdb, offS, ssrcS, snrmS, dinvS, bs,
                                                offD, ssrcD, snrmD, dinvD, bd, out, xcat);

  // fused = xcat @ wft^T + bf  -> d_out[2*N*O ..]
  gemm_f_k<<<dim3(2, 157), 256, 0, stream>>>(xcat, wft, out + (size_t)2 * N_NODES * O_DIM, bf_);
}

// Round 5
// 1062.383 us; speedup vs baseline: 1.1124x; 1.1124x over previous
//
#include <hip/hip_runtime.h>
#include <cstdint>
#include <cstddef>

typedef unsigned short u16;
typedef __bf16 bf16x8 __attribute__((ext_vector_type(8)));
typedef float f32x4 __attribute__((ext_vector_type(4)));

#define N_NODES 20000
#define MPAD    20096      // 157 * 128
#define E_EDGES 640000
#define K1      3000
#define K1P     3008       // 47 * 64
#define H_DIM   512
#define NW      1024       // W1|W2 fused width
#define O_DIM   256

__device__ __forceinline__ float bf2f(unsigned int hi) {
  union { unsigned int u; float f; } v; v.u = hi << 16; return v.f;
}
__device__ __forceinline__ u16 f2bf(float f) {
  union { float f; unsigned int u; } v; v.f = f;
  unsigned int u = v.u;
  return (u16)((u + 0x7fffu + ((u >> 16) & 1u)) >> 16);
}

__device__ __forceinline__ void gl2lds16(const void* g, void* l) {
  __builtin_amdgcn_global_load_lds((const __attribute__((address_space(1))) void*)g,
                                   (__attribute__((address_space(3))) void*)l, 16, 0, 0);
}

// ---------------- edge preprocessing ----------------
__global__ __launch_bounds__(256) void deg_init_k(float* degS, float* degD, int* cntS, int* cntD) {
  int i = blockIdx.x * 256 + threadIdx.x;
  if (i < N_NODES) { degS[i] = 1.0f; degD[i] = 1.0f; cntS[i] = 0; cntD[i] = 0; }
}

__global__ __launch_bounds__(256) void deg_accum_k(const int* eiS, const float* ewS,
                                                   const int* eiD, const float* ewD,
                                                   float* degS, float* degD, int* cntS, int* cntD) {
  int e = blockIdx.x * 256 + threadIdx.x;
  if (e < E_EDGES) {
    int cs = eiS[E_EDGES + e];
    atomicAdd(&degS[cs], ewS[e]);
    atomicAdd(&cntS[cs], 1);
    int cd = eiD[E_EDGES + e];
    atomicAdd(&degD[cd], ewD[e]);
    atomicAdd(&cntD[cd], 1);
  }
}

__global__ __launch_bounds__(256) void dinv_k(const float* degS, const float* degD,
                                              float* dinvS, float* dinvD) {
  int i = blockIdx.x * 256 + threadIdx.x;
  if (i < N_NODES) { dinvS[i] = rsqrtf(degS[i]); dinvD[i] = rsqrtf(degD[i]); }
}

__global__ __launch_bounds__(1024) void scan_k(const int* cntS, int* offS, int* curS,
                                               const int* cntD, int* offD, int* curD) {
  const int* cnt = blockIdx.x ? cntD : cntS;
  int* off = blockIdx.x ? offD : offS;
  int* cur = blockIdx.x ? curD : curS;
  __shared__ int sums[1024];
  const int t = threadIdx.x;
  const int CH = 20;
  int base = t * CH;
  int s = 0;
  for (int j = 0; j < CH; ++j) { int idx = base + j; if (idx < N_NODES) s += cnt[idx]; }
  sums[t] = s;
  __syncthreads();
  for (int d = 1; d < 1024; d <<= 1) {
    int v = (t >= d) ? sums[t - d] : 0;
    __syncthreads();
    sums[t] += v;
    __syncthreads();
  }
  int run = sums[t] - s;   // exclusive prefix
  for (int j = 0; j < CH; ++j) {
    int idx = base + j;
    if (idx <= N_NODES) {
      off[idx] = run; cur[idx] = run;
      if (idx < N_NODES) run += cnt[idx];
    }
  }
}

__global__ __launch_bounds__(256) void scatter_k(const int* eiS, const float* ewS, const float* dinvS,
                                                 int* curS, int* ssrcS, float* snrmS,
                                                 const int* eiD, const float* ewD, const float* dinvD,
                                                 int* curD, int* ssrcD, float* snrmD) {
  int e = blockIdx.x * 256 + threadIdx.x;
  if (e < E_EDGES) {
    {
      int r = eiS[e], c = eiS[E_EDGES + e];
      int pos = atomicAdd(&curS[c], 1);
      ssrcS[pos] = r;
      snrmS[pos] = dinvS[r] * ewS[e] * dinvS[c];
    }
    {
      int r = eiD[e], c = eiD[E_EDGES + e];
      int pos = atomicAdd(&curD[c], 1);
      ssrcD[pos] = r;
      snrmD[pos] = dinvD[r] * ewD[e] * dinvD[c];
    }
  }
}

// ---------------- weight conversions ----------------
// W1,W2 [3000][512] -> w12t [1024][3008] bf16 (transposed, padded), LDS-tiled 64x64
__global__ __launch_bounds__(256) void conv_w12_k(const float* __restrict__ W1,
                                                  const float* __restrict__ W2,
                                                  u16* __restrict__ w12t) {
  __shared__ float t[64][65];
  const int kb = blockIdx.x;           // 0..46
  const int nb = blockIdx.y;           // 0..15
  const int n0 = nb * 64;
  const float* W = (n0 < H_DIM) ? W1 : W2;
  const int nn0 = n0 & (H_DIM - 1);
  const int k0 = kb * 64;
  const int tc = threadIdx.x & 63;
  const int tr4 = threadIdx.x >> 6;    // 0..3
#pragma unroll
  for (int rr = 0; rr < 16; ++rr) {
    int r = tr4 * 16 + rr;
    int k = k0 + r;
    t[r][tc] = (k < K1) ? W[(size_t)k * H_DIM + nn0 + tc] : 0.f;
  }
  __syncthreads();
#pragma unroll
  for (int rr = 0; rr < 16; ++rr) {
    int n = tr4 * 16 + rr;
    w12t[(size_t)(n0 + n) * K1P + k0 + tc] = f2bf(t[tc][n]);
  }
}

// Ws/Wd/Wf [512][256] -> [256][512] bf16, LDS-tiled 64x64
__global__ __launch_bounds__(256) void conv_wsm_k(const float* Ws, const float* Wd, const float* Wf,
                                                  u16* wst, u16* wdt, u16* wft) {
  __shared__ float t[64][65];
  const int which = blockIdx.z;
  const float* W = (which == 0) ? Ws : (which == 1) ? Wd : Wf;
  u16* o = (which == 0) ? wst : (which == 1) ? wdt : wft;
  const int k0 = blockIdx.x * 64;      // 0..448
  const int n0 = blockIdx.y * 64;      // 0..192
  const int tc = threadIdx.x & 63;
  const int tr4 = threadIdx.x >> 6;
#pragma unroll
  for (int rr = 0; rr < 16; ++rr) {
    int r = tr4 * 16 + rr;
    t[r][tc] = W[(size_t)(k0 + r) * O_DIM + n0 + tc];
  }
  __syncthreads();
#pragma unroll
  for (int rr = 0; rr < 16; ++rr) {
    int n = tr4 * 16 + rr;
    o[(size_t)(n0 + n) * H_DIM + k0 + tc] = f2bf(t[tc][n]);
  }
}

// ---------------- shared GEMM body: C[M,N] = A[M,K] * Bt[N,K]^T (bf16 in, fp32 acc) --------
// LDS layout: row-major [128][64] u16 with XOR granule swizzle: physical 16B-granule p of
// row r holds logical granule p ^ (r&7).  Staging picks global granule (tid&7)^((tid>>3)&7)
// so the wave-uniform global_load_lds dest (base + lane*16B) lands each granule at its
// swizzled position.  Fragment ds_read_b128 then hits 8 distinct bank-quads per 8-lane
// phase group -> conflict-free (measured 0 SQ_LDS_BANK_CONFLICT).
template <typename CT, bool BIAS>
__device__ __forceinline__ void gemm_body(const u16* __restrict__ A, const u16* __restrict__ Bt,
                                          CT* __restrict__ C, const float* __restrict__ bias,
                                          int Mreal, int K, int ldc) {
  __shared__ alignas(16) u16 As[128 * 64];
  __shared__ alignas(16) u16 Bs[128 * 64];
  const int tid = threadIdx.x;
  const int lane = tid & 63;
  const int wv = tid >> 6;
  const int bm = blockIdx.y * 128;
  const int bn = blockIdx.x * 128;

  const int wm = (wv >> 1) << 6;
  const int wn = (wv & 1) << 6;
  const int frow = lane & 15;
  const int q = lane >> 4;             // logical granule base (0..3)
  const int r7 = lane & 7;             // row&7 for all fragment rows this lane touches

  const int srow = tid >> 3;           // 0..31
  const int sgr = ((tid & 7) ^ ((tid >> 3) & 7)) << 3;   // swizzled granule * 8 u16
  const u16* ga = A + (size_t)(bm + srow) * K + sgr;
  const u16* gb = Bt + (size_t)(bn + srow) * K + sgr;
  u16* la = &As[wv * 512];
  u16* lb = &Bs[wv * 512];

  f32x4 acc[4][4] = {};

  for (int k0 = 0; k0 < K; k0 += 64) {
#pragma unroll
    for (int r = 0; r < 4; ++r) {
      gl2lds16(ga + (size_t)(r * 32) * K + k0, la + r * 2048);
      gl2lds16(gb + (size_t)(r * 32) * K + k0, lb + r * 2048);
    }
    __syncthreads();
#pragma unroll
    for (int ks = 0; ks < 64; ks += 32) {
      const int p = (((q + (ks >> 3)) ^ r7) << 3);   // physical u16 offset within row
      bf16x8 af[4], bv[4];
#pragma unroll
      for (int t = 0; t < 4; ++t) {
        af[t] = *(const bf16x8*)&As[(wm + t * 16 + frow) * 64 + p];
        bv[t] = *(const bf16x8*)&Bs[(wn + t * 16 + frow) * 64 + p];
      }
#pragma unroll
      for (int i = 0; i < 4; ++i)
#pragma unroll
        for (int j = 0; j < 4; ++j)
          acc[i][j] = __builtin_amdgcn_mfma_f32_16x16x32_bf16(af[i], bv[j], acc[i][j], 0, 0, 0);
    }
    __syncthreads();
  }

  // C/D layout (m89-verified): col = lane&15, row = (lane>>4)*4 + reg
  const int crow = (lane >> 4) << 2;
  const int ccol = lane & 15;
#pragma unroll
  for (int i = 0; i < 4; ++i) {
#pragma unroll
    for (int r = 0; r < 4; ++r) {
      int gr = bm + wm + i * 16 + crow + r;
      if (gr < Mreal) {
#pragma unroll
        for (int j = 0; j < 4; ++j) {
          int gc = bn + wn + j * 16 + ccol;
          float v = acc[i][j][r];
          if constexpr (BIAS) v += bias[gc];
          if constexpr (sizeof(CT) == 2) C[(size_t)gr * ldc + gc] = (CT)f2bf(v);
          else C[(size_t)gr * ldc + gc] = (CT)v;
        }
      }
    }
  }
}

// middle pair: hsb = xs@Ws^T, hdb = xd@Wd^T in one dispatch (z selects), grid (2,157,2)
__global__ __launch_bounds__(256) void gemm_pair_k(const u16* A0, const u16* B0, u16* C0,
                                                   const u16* A1, const u16* B1, u16* C1) {
  const u16* A = blockIdx.z ? A1 : A0;
  const u16* Bt = blockIdx.z ? B1 : B0;
  u16* C = blockIdx.z ? C1 : C0;
  gemm_body<u16, false>(A, Bt, C, nullptr, N_NODES, H_DIM, O_DIM);
}

// final: fused = xcat @ wft^T + bf (float out)
__global__ __launch_bounds__(256) void gemm_f_k(const u16* A, const u16* Bt, float* C,
                                                const float* bias) {
  gemm_body<float, true>(A, Bt, C, bias, N_NODES, H_DIM, O_DIM);
}

// ---------------- fused big GEMM v3: h12 = bf16(x) @ w12t^T, A staged as RAW F32 DMA ------
// R4 lesson: reg-staging A serializes (load->cvt->ds_write on the critical path) and dbuf
// LDS killed occupancy.  v3 keeps the PROVEN single-buffer 2-barrier structure and the
// global_load_lds DMA path for BOTH operands; A is staged as f32 (32KB tile) and converted
// to bf16 in the fragment-read path (2x ds_read_b128 + 8 casts per fragment).
//
// A LDS layout: [128][64] f32, 16B-granule XOR swizzle: phys granule p (0..15) of row r
// holds logical granule p ^ (r&7).  Staging call c (0..7): thread covers row = (tid>>4)+c*16,
// phys granule tid&15 -> per-lane SOURCE granule lg = (tid&15) ^ (row&7)  ((c*16)&7==0 so
// row&7 == (tid>>4)&7); LDS dest = wave-uniform Asf + c*1024 + wv*256 (+ lane*16B by HW).
// Fragment read: logical f32 granules G0=(q+4*ks32)*2, G0+1 at phys G^r7 -> per-b128 the
// lane->bank pattern is IDENTICAL to the proven conflict-free bf16 pattern.
// K-tail: granules with k0 + lg*4 >= 3000 redirect to col 0 (finite) x B==0 -> 0.
// Row-tail >= 20000 -> row 0, discarded by the C-write guard.
__global__ __launch_bounds__(256) void gemm_xf_k(const float* __restrict__ X,
                                                 const u16* __restrict__ Bt,
                                                 u16* __restrict__ C) {
  __shared__ alignas(16) float Asf[128 * 64];   // 32 KB
  __shared__ alignas(16) u16 Bs[128 * 64];      // 16 KB
  const int tid = threadIdx.x;
  const int lane = tid & 63;
  const int wv = tid >> 6;

  // XCD chunk swizzle (nwg = 8*157 = 1256, %8 == 0): per-XCD contiguous M-chunk across all
  // 8 N-blocks -> A-panel reuse is L2-local (measured FETCH 478->119 MB on the bf16 path).
  const int h = blockIdx.y * 8 + blockIdx.x;
  const int chunk = 157;               // 1256 / 8
  const int L = (h & 7) * chunk + (h >> 3);
  const int bn = (L & 7) * 128;
  const int bm = (L >> 3) * 128;

  const int wm = (wv >> 1) << 6;
  const int wn = (wv & 1) << 6;
  const int frow = lane & 15;
  const int q = lane >> 4;
  const int r7 = lane & 7;

  // ---- A staging geometry (f32) ----
  const int arow = tid >> 4;                     // 0..15
  const int lg = (tid & 15) ^ (arow & 7);        // logical f32 granule (4 floats)
  const int thr = K1 - lg * 4;                   // k0 >= thr -> this lane's granule OOB
  const int negc = -(lg * 4);                    // redirect offset -> column 0
  const float* xa[8];
#pragma unroll
  for (int c = 0; c < 8; ++c) {
    int row = bm + arow + c * 16;
    if (row >= N_NODES) row = 0;                 // discarded rows -> safe source
    xa[c] = X + (size_t)row * K1 + lg * 4;
  }

  // ---- B staging geometry (proven bf16 path) ----
  const int srow = tid >> 3;                     // 0..31
  const int sgr = ((tid & 7) ^ ((tid >> 3) & 7)) << 3;
  const u16* gb = Bt + (size_t)(bn + srow) * K1P + sgr;
  u16* lb = &Bs[wv * 512];
  float* laf = Asf + wv * 256;                   // + c*1024 per call

  f32x4 acc[4][4] = {};

  for (int k0 = 0; k0 < K1P; k0 += 64) {
    const int kof = (k0 >= thr) ? negc : k0;     // per-lane K-tail redirect
#pragma unroll
    for (int r = 0; r < 4; ++r)
      gl2lds16(gb + (size_t)(r * 32) * K1P + k0, lb + r * 2048);
#pragma unroll
    for (int c = 0; c < 8; ++c)
      gl2lds16(xa[c] + kof, laf + c * 1024);
    __syncthreads();
#pragma unroll
    for (int ks32 = 0; ks32 < 2; ++ks32) {
      const int p = (((q + ks32 * 4) ^ r7) << 3);      // B: physical u16 offset within row
      const int G0 = (q + ks32 * 4) * 2;               // A: logical f32 granule base
      bf16x8 af[4], bv[4];
#pragma unroll
      for (int t = 0; t < 4; ++t) {
        const int R = wm + t * 16 + frow;
        f32x4 a0 = *(const f32x4*)&Asf[R * 64 + ((G0 ^ r7) << 2)];
        f32x4 a1 = *(const f32x4*)&Asf[R * 64 + (((G0 + 1) ^ r7) << 2)];
        bf16x8 pk;
        pk[0] = (__bf16)a0[0]; pk[1] = (__bf16)a0[1]; pk[2] = (__bf16)a0[2]; pk[3] = (__bf16)a0[3];
        pk[4] = (__bf16)a1[0]; pk[5] = (__bf16)a1[1]; pk[6] = (__bf16)a1[2]; pk[7] = (__bf16)a1[3];
        af[t] = pk;
        bv[t] = *(const bf16x8*)&Bs[(wn + t * 16 + frow) * 64 + p];
      }
#pragma unroll
      for (int i = 0; i < 4; ++i)
#pragma unroll
        for (int j = 0; j < 4; ++j)
          acc[i][j] = __builtin_amdgcn_mfma_f32_16x16x32_bf16(af[i], bv[j], acc[i][j], 0, 0, 0);
    }
    __syncthreads();
  }

  const int crow = (lane >> 4) << 2;
  const int ccol = lane & 15;
#pragma unroll
  for (int i = 0; i < 4; ++i) {
#pragma unroll
    for (int r = 0; r < 4; ++r) {
      int gr = bm + wm + i * 16 + crow + r;
      if (gr < N_NODES) {
#pragma unroll
        for (int j = 0; j < 4; ++j) {
          int gc = bn + wn + j * 16 + ccol;
          C[(size_t)gr * NW + gc] = f2bf(acc[i][j][r]);
        }
      }
    }
  }
}

// ---------------- aggregation layer 1 ----------------
// Edge loop unrolled x4: batch the src/nrm loads, then issue all 4 row-gathers
// back-to-back before consuming -> ~4x the in-flight VMEM per wave (latency-bound fix).
__global__ __launch_bounds__(256) void agg1_k(const u16* __restrict__ h12,
                                              const int* offS, const int* srcS, const float* nrmS,
                                              const float* dinvS, const float* b1,
                                              const int* offD, const int* srcD, const float* nrmD,
                                              const float* dinvD, const float* b2,
                                              u16* __restrict__ xsd) {
  const int lane = threadIdx.x & 63;
  const int wv = threadIdx.x >> 6;
  const int i = blockIdx.x * 4 + wv;       // node (0..MPAD)
  const int g = blockIdx.y;
  if (i >= MPAD) return;
  u16* outp = xsd + ((size_t)g * MPAD + i) * H_DIM + lane * 8;
  if (i >= N_NODES) { uint4 z = {0, 0, 0, 0}; *(uint4*)outp = z; return; }

  const int* off = g ? offD : offS;
  const int* src = g ? srcD : srcS;
  const float* nrm = g ? nrmD : nrmS;
  const float* dinv = g ? dinvD : dinvS;
  const float* bias = g ? b2 : b1;
  const u16* hb = h12 + (size_t)g * H_DIM + lane * 8;

  float a[8];
  float dv = dinv[i];
  float sw = dv * dv;
  uint4 u = *(const uint4*)(hb + (size_t)i * NW);
  a[0] = sw * bf2f(u.x & 0xffff); a[1] = sw * bf2f(u.x >> 16);
  a[2] = sw * bf2f(u.y & 0xffff); a[3] = sw * bf2f(u.y >> 16);
  a[4] = sw * bf2f(u.z & 0xffff); a[5] = sw * bf2f(u.z >> 16);
  a[6] = sw * bf2f(u.w & 0xffff); a[7] = sw * bf2f(u.w >> 16);

  const int e0 = off[i], e1 = off[i + 1];
  int e = e0;
  for (; e + 4 <= e1; e += 4) {
    int ss[4]; float ww[4];
#pragma unroll
    for (int t = 0; t < 4; ++t) { ss[t] = src[e + t]; ww[t] = nrm[e + t]; }
    uint4 vv[4];
#pragma unroll
    for (int t = 0; t < 4; ++t) vv[t] = *(const uint4*)(hb + (size_t)ss[t] * NW);
#pragma unroll
    for (int t = 0; t < 4; ++t) {
      float w = ww[t]; uint4 v = vv[t];
      a[0] += w * bf2f(v.x & 0xffff); a[1] += w * bf2f(v.x >> 16);
      a[2] += w * bf2f(v.y & 0xffff); a[3] += w * bf2f(v.y >> 16);
      a[4] += w * bf2f(v.z & 0xffff); a[5] += w * bf2f(v.z >> 16);
      a[6] += w * bf2f(v.w & 0xffff); a[7] += w * bf2f(v.w >> 16);
    }
  }
  for (; e < e1; ++e) {
    int s = src[e];
    float w = nrm[e];
    uint4 v = *(const uint4*)(hb + (size_t)s * NW);
    a[0] += w * bf2f(v.x & 0xffff); a[1] += w * bf2f(v.x >> 16);
    a[2] += w * bf2f(v.y & 0xffff); a[3] += w * bf2f(v.y >> 16);
    a[4] += w * bf2f(v.z & 0xffff); a[5] += w * bf2f(v.z >> 16);
    a[6] += w * bf2f(v.w & 0xffff); a[7] += w * bf2f(v.w >> 16);
  }
  float4 bA = *(const float4*)(bias + lane * 8);
  float4 bB = *(const float4*)(bias + lane * 8 + 4);
  a[0] = fmaxf(a[0] + bA.x, 0.f); a[1] = fmaxf(a[1] + bA.y, 0.f);
  a[2] = fmaxf(a[2] + bA.z, 0.f); a[3] = fmaxf(a[3] + bA.w, 0.f);
  a[4] = fmaxf(a[4] + bB.x, 0.f); a[5] = fmaxf(a[5] + bB.y, 0.f);
  a[6] = fmaxf(a[6] + bB.z, 0.f); a[7] = fmaxf(a[7] + bB.w, 0.f);
  uint4 o;
  o.x = f2bf(a[0]) | ((unsigned)f2bf(a[1]) << 16);
  o.y = f2bf(a[2]) | ((unsigned)f2bf(a[3]) << 16);
  o.z = f2bf(a[4]) | ((unsigned)f2bf(a[5]) << 16);
  o.w = f2bf(a[6]) | ((unsigned)f2bf(a[7]) << 16);
  *(uint4*)outp = o;
}

// ---------------- aggregation layer 2 ----------------
__global__ __launch_bounds__(256) void agg2_k(const u16* __restrict__ hsb, const u16* __restrict__ hdb,
                                              const int* offS, const int* srcS, const float* nrmS,
                                              const float* dinvS, const float* bs,
                                              const int* offD, const int* srcD, const float* nrmD,
                                              const float* dinvD, const float* bd,
                                              float* __restrict__ outF, u16* __restrict__ xcat) {
  const int lane = threadIdx.x & 63;
  const int wv = threadIdx.x >> 6;
  const int i = blockIdx.x * 4 + wv;
  const int g = blockIdx.y;
  if (i >= MPAD) return;
  u16* oc = xcat + (size_t)i * H_DIM + (size_t)g * O_DIM + lane * 4;
  if (i >= N_NODES) { uint2 z = {0, 0}; *(uint2*)oc = z; return; }

  const u16* h = g ? hdb : hsb;
  const int* off = g ? offD : offS;
  const int* src = g ? srcD : srcS;
  const float* nrm = g ? nrmD : nrmS;
  const float* dinv = g ? dinvD : dinvS;
  const float* bias = g ? bd : bs;
  const u16* hb = h + lane * 4;

  float a[4];
  float dv = dinv[i];
  float sw = dv * dv;
  uint2 u = *(const uint2*)(hb + (size_t)i * O_DIM);
  a[0] = sw * bf2f(u.x & 0xffff); a[1] = sw * bf2f(u.x >> 16);
  a[2] = sw * bf2f(u.y & 0xffff); a[3] = sw * bf2f(u.y >> 16);

  const int e0 = off[i], e1 = off[i + 1];
  int e = e0;
  for (; e + 8 <= e1; e += 8) {
    int ss[8]; float ww[8];
#pragma unroll
    for (int t = 0; t < 8; ++t) { ss[t] = src[e + t]; ww[t] = nrm[e + t]; }
    uint2 vv[8];
#pragma unroll
    for (int t = 0; t < 8; ++t) vv[t] = *(const uint2*)(hb + (size_t)ss[t] * O_DIM);
#pragma unroll
    for (int t = 0; t < 8; ++t) {
      float w = ww[t]; uint2 v = vv[t];
      a[0] += w * bf2f(v.x & 0xffff); a[1] += w * bf2f(v.x >> 16);
      a[2] += w * bf2f(v.y & 0xffff); a[3] += w * bf2f(v.y >> 16);
    }
  }
  for (; e < e1; ++e) {
    int s = src[e];
    float w = nrm[e];
    uint2 v = *(const uint2*)(hb + (size_t)s * O_DIM);
    a[0] += w * bf2f(v.x & 0xffff); a[1] += w * bf2f(v.x >> 16);
    a[2] += w * bf2f(v.y & 0xffff); a[3] += w * bf2f(v.y >> 16);
  }
  float4 bb = *(const float4*)(bias + lane * 4);
  a[0] += bb.x; a[1] += bb.y; a[2] += bb.z; a[3] += bb.w;

  float4 fo = {a[0], a[1], a[2], a[3]};
  *(float4*)(outF + (size_t)g * N_NODES * O_DIM + (size_t)i * O_DIM + lane * 4) = fo;
  uint2 o;
  o.x = f2bf(a[0]) | ((unsigned)f2bf(a[1]) << 16);
  o.y = f2bf(a[2]) | ((unsigned)f2bf(a[3]) << 16);
  *(uint2*)oc = o;
}

// ---------------- launch ----------------
extern "C" void kernel_launch(void* const* d_in, const int* in_sizes, int n_in,
                              void* d_out, int out_size, void* d_ws, size_t ws_size,
                              hipStream_t stream) {
  const float* x = (const float*)d_in[0];
  const int* eiS = (const int*)d_in[1];
  const float* ewS = (const float*)d_in[2];
  const int* eiD = (const int*)d_in[3];
  const float* ewD = (const float*)d_in[4];
  const float* W1 = (const float*)d_in[5];
  const float* b1 = (const float*)d_in[6];
  const float* W2 = (const float*)d_in[7];
  const float* b2 = (const float*)d_in[8];
  const float* Ws = (const float*)d_in[9];
  const float* bs = (const float*)d_in[10];
  const float* Wd = (const float*)d_in[11];
  const float* bd = (const float*)d_in[12];
  const float* Wf = (const float*)d_in[13];
  const float* bf_ = (const float*)d_in[14];
  float* out = (float*)d_out;

  char* p = (char*)d_ws;
  auto alloc = [&](size_t n) -> char* { char* r = p; p += (n + 255) & ~(size_t)255; return r; };

  u16* w12t  = (u16*)alloc((size_t)NW * K1P * 2);
  u16* h12   = (u16*)alloc((size_t)N_NODES * NW * 2);
  u16* xsd   = (u16*)alloc((size_t)2 * MPAD * H_DIM * 2);
  u16* hsb   = (u16*)alloc((size_t)N_NODES * O_DIM * 2);
  u16* hdb   = (u16*)alloc((size_t)N_NODES * O_DIM * 2);
  u16* xcat  = (u16*)alloc((size_t)MPAD * H_DIM * 2);
  u16* wst   = (u16*)alloc((size_t)O_DIM * H_DIM * 2);
  u16* wdt   = (u16*)alloc((size_t)O_DIM * H_DIM * 2);
  u16* wft   = (u16*)alloc((size_t)O_DIM * H_DIM * 2);
  float* degS = (float*)alloc((size_t)N_NODES * 4);
  float* degD = (float*)alloc((size_t)N_NODES * 4);
  float* dinvS = (float*)alloc((size_t)N_NODES * 4);
  float* dinvD = (float*)alloc((size_t)N_NODES * 4);
  int* cntS = (int*)alloc((size_t)N_NODES * 4);
  int* cntD = (int*)alloc((size_t)N_NODES * 4);
  int* offS = (int*)alloc((size_t)(N_NODES + 1) * 4);
  int* offD = (int*)alloc((size_t)(N_NODES + 1) * 4);
  int* curS = (int*)alloc((size_t)(N_NODES + 1) * 4);
  int* curD = (int*)alloc((size_t)(N_NODES + 1) * 4);
  int* ssrcS = (int*)alloc((size_t)E_EDGES * 4);
  int* ssrcD = (int*)alloc((size_t)E_EDGES * 4);
  float* snrmS = (float*)alloc((size_t)E_EDGES * 4);
  float* snrmD = (float*)alloc((size_t)E_EDGES * 4);

  const int gN = (N_NODES + 255) / 256;     // 79
  const int gE = (E_EDGES + 255) / 256;     // 2500

  deg_init_k<<<gN, 256, 0, stream>>>(degS, degD, cntS, cntD);
  deg_accum_k<<<gE, 256, 0, stream>>>(eiS, ewS, eiD, ewD, degS, degD, cntS, cntD);
  dinv_k<<<gN, 256, 0, stream>>>(degS, degD, dinvS, dinvD);
  scan_k<<<2, 1024, 0, stream>>>(cntS, offS, curS, cntD, offD, curD);
  scatter_k<<<gE, 256, 0, stream>>>(eiS, ewS, dinvS, curS, ssrcS, snrmS,
                                    eiD, ewD, dinvD, curD, ssrcD, snrmD);

  conv_w12_k<<<dim3(47, 16), 256, 0, stream>>>(W1, W2, w12t);
  conv_wsm_k<<<dim3(8, 4, 3), 256, 0, stream>>>(Ws, Wd, Wf, wst, wdt, wft);

  // h12 = bf16(x) @ w12t^T  [20000 x 1024]; A staged as raw f32 DMA, cvt in read path
  gemm_xf_k<<<dim3(8, 157), 256, 0, stream>>>(x, w12t, h12);

  agg1_k<<<dim3(MPAD / 4, 2), 256, 0, stream>>>(h12, offS, ssrcS, snrmS, dinvS, b1,
                                                offD, ssrcD, snrmD, dinvD, b2, xsd);

  // hsb = xs @ Ws^T and hdb = xd @ Wd^T in one dispatch (628 blocks)
  gemm_pair_k<<<dim3(2, 157, 2), 256, 0, stream>>>(xsd, wst, hsb,
                                                   xsd + (size_t)MPAD * H_DIM, wdt, hdb);

  agg2_k<<<dim3(MPAD / 4, 2), 256, 0, stream>>>(hsb, hdb, offS, ssrcS, snrmS, dinvS, bs,
                                                offD, ssrcD, snrmD, dinvD, bd, out, xcat);

  // fused = xcat @ wft^T + bf  -> d_out[2*N*O ..]
  gemm_f_k<<<dim3(2, 157), 256, 0, stream>>>(xcat, wft, out + (size_t)2 * N_NODES * O_DIM, bf_);
}

// Round 6
// 1052.144 us; speedup vs baseline: 1.1232x; 1.0097x over previous
//
#include <hip/hip_runtime.h>
#include <cstdint>
#include <cstddef>

typedef unsigned short u16;
typedef __bf16 bf16x8 __attribute__((ext_vector_type(8)));
typedef float f32x4 __attribute__((ext_vector_type(4)));

#define N_NODES 20000
#define MPAD    20096      // 157 * 128
#define E_EDGES 640000
#define K1      3000
#define K1P     3008       // 47 * 64
#define H_DIM   512
#define NW      1024       // W1|W2 fused width
#define O_DIM   256

__device__ __forceinline__ float bf2f(unsigned int hi) {
  union { unsigned int u; float f; } v; v.u = hi << 16; return v.f;
}
__device__ __forceinline__ u16 f2bf(float f) {
  union { float f; unsigned int u; } v; v.f = f;
  unsigned int u = v.u;
  return (u16)((u + 0x7fffu + ((u >> 16) & 1u)) >> 16);
}

__device__ __forceinline__ void gl2lds16(const void* g, void* l) {
  __builtin_amdgcn_global_load_lds((const __attribute__((address_space(1))) void*)g,
                                   (__attribute__((address_space(3))) void*)l, 16, 0, 0);
}

// ---------------- edge preprocessing ----------------
__global__ __launch_bounds__(256) void deg_init_k(float* degS, float* degD, int* cntS, int* cntD) {
  int i = blockIdx.x * 256 + threadIdx.x;
  if (i < N_NODES) { degS[i] = 1.0f; degD[i] = 1.0f; cntS[i] = 0; cntD[i] = 0; }
}

__global__ __launch_bounds__(256) void deg_accum_k(const int* eiS, const float* ewS,
                                                   const int* eiD, const float* ewD,
                                                   float* degS, float* degD, int* cntS, int* cntD) {
  int e = blockIdx.x * 256 + threadIdx.x;
  if (e < E_EDGES) {
    int cs = eiS[E_EDGES + e];
    atomicAdd(&degS[cs], ewS[e]);
    atomicAdd(&cntS[cs], 1);
    int cd = eiD[E_EDGES + e];
    atomicAdd(&degD[cd], ewD[e]);
    atomicAdd(&cntD[cd], 1);
  }
}

__global__ __launch_bounds__(256) void dinv_k(const float* degS, const float* degD,
                                              float* dinvS, float* dinvD) {
  int i = blockIdx.x * 256 + threadIdx.x;
  if (i < N_NODES) { dinvS[i] = rsqrtf(degS[i]); dinvD[i] = rsqrtf(degD[i]); }
}

__global__ __launch_bounds__(1024) void scan_k(const int* cntS, int* offS, int* curS,
                                               const int* cntD, int* offD, int* curD) {
  const int* cnt = blockIdx.x ? cntD : cntS;
  int* off = blockIdx.x ? offD : offS;
  int* cur = blockIdx.x ? curD : curS;
  __shared__ int sums[1024];
  const int t = threadIdx.x;
  const int CH = 20;
  int base = t * CH;
  int s = 0;
  for (int j = 0; j < CH; ++j) { int idx = base + j; if (idx < N_NODES) s += cnt[idx]; }
  sums[t] = s;
  __syncthreads();
  for (int d = 1; d < 1024; d <<= 1) {
    int v = (t >= d) ? sums[t - d] : 0;
    __syncthreads();
    sums[t] += v;
    __syncthreads();
  }
  int run = sums[t] - s;   // exclusive prefix
  for (int j = 0; j < CH; ++j) {
    int idx = base + j;
    if (idx <= N_NODES) {
      off[idx] = run; cur[idx] = run;
      if (idx < N_NODES) run += cnt[idx];
    }
  }
}

__global__ __launch_bounds__(256) void scatter_k(const int* eiS, const float* ewS, const float* dinvS,
                                                 int* curS, int* ssrcS, float* snrmS,
                                                 const int* eiD, const float* ewD, const float* dinvD,
                                                 int* curD, int* ssrcD, float* snrmD) {
  int e = blockIdx.x * 256 + threadIdx.x;
  if (e < E_EDGES) {
    {
      int r = eiS[e], c = eiS[E_EDGES + e];
      int pos = atomicAdd(&curS[c], 1);
      ssrcS[pos] = r;
      snrmS[pos] = dinvS[r] * ewS[e] * dinvS[c];
    }
    {
      int r = eiD[e], c = eiD[E_EDGES + e];
      int pos = atomicAdd(&curD[c], 1);
      ssrcD[pos] = r;
      snrmD[pos] = dinvD[r] * ewD[e] * dinvD[c];
    }
  }
}

// ---------------- conversions ----------------
// x [20000][3000] f32 -> xb [MPAD][K1P] bf16 (zero-padded).  3000 = 375*8 exactly.
// (R3-R5 tried fusing this into the GEMM three ways; all lost to this split because the
// bf16 global_load_lds staging path is what makes the 172us GEMM work.  Keep split.)
__global__ __launch_bounds__(256) void conv_x_k(const float* __restrict__ x, u16* __restrict__ xb) {
  const int row = blockIdx.x;
  for (int c = threadIdx.x; c < 376; c += 256) {
    uint4 o = {0, 0, 0, 0};
    if (row < N_NODES && c < 375) {
      const float4* p = (const float4*)(x + (size_t)row * K1 + (size_t)c * 8);
      float4 v0 = p[0], v1 = p[1];
      o.x = f2bf(v0.x) | ((unsigned)f2bf(v0.y) << 16);
      o.y = f2bf(v0.z) | ((unsigned)f2bf(v0.w) << 16);
      o.z = f2bf(v1.x) | ((unsigned)f2bf(v1.y) << 16);
      o.w = f2bf(v1.z) | ((unsigned)f2bf(v1.w) << 16);
    }
    *(uint4*)(xb + (size_t)row * K1P + (size_t)c * 8) = o;
  }
}

// W1,W2 [3000][512] -> w12t [1024][3008] bf16 (transposed, padded), LDS-tiled 64x64
__global__ __launch_bounds__(256) void conv_w12_k(const float* __restrict__ W1,
                                                  const float* __restrict__ W2,
                                                  u16* __restrict__ w12t) {
  __shared__ float t[64][65];
  const int kb = blockIdx.x;           // 0..46
  const int nb = blockIdx.y;           // 0..15
  const int n0 = nb * 64;
  const float* W = (n0 < H_DIM) ? W1 : W2;
  const int nn0 = n0 & (H_DIM - 1);
  const int k0 = kb * 64;
  const int tc = threadIdx.x & 63;
  const int tr4 = threadIdx.x >> 6;    // 0..3
#pragma unroll
  for (int rr = 0; rr < 16; ++rr) {
    int r = tr4 * 16 + rr;
    int k = k0 + r;
    t[r][tc] = (k < K1) ? W[(size_t)k * H_DIM + nn0 + tc] : 0.f;
  }
  __syncthreads();
#pragma unroll
  for (int rr = 0; rr < 16; ++rr) {
    int n = tr4 * 16 + rr;
    w12t[(size_t)(n0 + n) * K1P + k0 + tc] = f2bf(t[tc][n]);
  }
}

// Ws/Wd/Wf [512][256] -> [256][512] bf16, LDS-tiled 64x64
__global__ __launch_bounds__(256) void conv_wsm_k(const float* Ws, const float* Wd, const float* Wf,
                                                  u16* wst, u16* wdt, u16* wft) {
  __shared__ float t[64][65];
  const int which = blockIdx.z;
  const float* W = (which == 0) ? Ws : (which == 1) ? Wd : Wf;
  u16* o = (which == 0) ? wst : (which == 1) ? wdt : wft;
  const int k0 = blockIdx.x * 64;      // 0..448
  const int n0 = blockIdx.y * 64;      // 0..192
  const int tc = threadIdx.x & 63;
  const int tr4 = threadIdx.x >> 6;
#pragma unroll
  for (int rr = 0; rr < 16; ++rr) {
    int r = tr4 * 16 + rr;
    t[r][tc] = W[(size_t)(k0 + r) * O_DIM + n0 + tc];
  }
  __syncthreads();
#pragma unroll
  for (int rr = 0; rr < 16; ++rr) {
    int n = tr4 * 16 + rr;
    o[(size_t)(n0 + n) * H_DIM + k0 + tc] = f2bf(t[tc][n]);
  }
}

// ---------------- shared GEMM body: C[M,N] = A[M,K] * Bt[N,K]^T (bf16 in, fp32 acc) --------
// LDS layout: row-major [128][64] u16 with XOR granule swizzle: physical 16B-granule p of
// row r holds logical granule p ^ (r&7).  Staging picks global granule (tid&7)^((tid>>3)&7)
// so the wave-uniform global_load_lds dest (base + lane*16B) lands each granule at its
// swizzled position.  Fragment ds_read_b128 then hits 8 distinct bank-quads per 8-lane
// phase group -> conflict-free (measured 0 SQ_LDS_BANK_CONFLICT).
template <typename CT, bool BIAS>
__device__ __forceinline__ void gemm_body(const u16* __restrict__ A, const u16* __restrict__ Bt,
                                          CT* __restrict__ C, const float* __restrict__ bias,
                                          int Mreal, int K, int ldc, int bm, int bn) {
  __shared__ alignas(16) u16 As[128 * 64];
  __shared__ alignas(16) u16 Bs[128 * 64];
  const int tid = threadIdx.x;
  const int lane = tid & 63;
  const int wv = tid >> 6;

  const int wm = (wv >> 1) << 6;
  const int wn = (wv & 1) << 6;
  const int frow = lane & 15;
  const int q = lane >> 4;             // logical granule base (0..3)
  const int r7 = lane & 7;             // row&7 for all fragment rows this lane touches

  const int srow = tid >> 3;           // 0..31
  const int sgr = ((tid & 7) ^ ((tid >> 3) & 7)) << 3;   // swizzled granule * 8 u16
  const u16* ga = A + (size_t)(bm + srow) * K + sgr;
  const u16* gb = Bt + (size_t)(bn + srow) * K + sgr;
  u16* la = &As[wv * 512];
  u16* lb = &Bs[wv * 512];

  f32x4 acc[4][4] = {};

  for (int k0 = 0; k0 < K; k0 += 64) {
#pragma unroll
    for (int r = 0; r < 4; ++r) {
      gl2lds16(ga + (size_t)(r * 32) * K + k0, la + r * 2048);
      gl2lds16(gb + (size_t)(r * 32) * K + k0, lb + r * 2048);
    }
    __syncthreads();
#pragma unroll
    for (int ks = 0; ks < 64; ks += 32) {
      const int p = (((q + (ks >> 3)) ^ r7) << 3);   // physical u16 offset within row
      bf16x8 af[4], bv[4];
#pragma unroll
      for (int t = 0; t < 4; ++t) {
        af[t] = *(const bf16x8*)&As[(wm + t * 16 + frow) * 64 + p];
        bv[t] = *(const bf16x8*)&Bs[(wn + t * 16 + frow) * 64 + p];
      }
#pragma unroll
      for (int i = 0; i < 4; ++i)
#pragma unroll
        for (int j = 0; j < 4; ++j)
          acc[i][j] = __builtin_amdgcn_mfma_f32_16x16x32_bf16(af[i], bv[j], acc[i][j], 0, 0, 0);
    }
    __syncthreads();
  }

  // C/D layout (m89-verified): col = lane&15, row = (lane>>4)*4 + reg
  const int crow = (lane >> 4) << 2;
  const int ccol = lane & 15;
#pragma unroll
  for (int i = 0; i < 4; ++i) {
#pragma unroll
    for (int r = 0; r < 4; ++r) {
      int gr = bm + wm + i * 16 + crow + r;
      if (gr < Mreal) {
#pragma unroll
        for (int j = 0; j < 4; ++j) {
          int gc = bn + wn + j * 16 + ccol;
          float v = acc[i][j][r];
          if constexpr (BIAS) v += bias[gc];
          if constexpr (sizeof(CT) == 2) C[(size_t)gr * ldc + gc] = (CT)f2bf(v);
          else C[(size_t)gr * ldc + gc] = (CT)v;
        }
      }
    }
  }
}

// big GEMM: h12 = xb @ w12t^T [20096 x 1024], XCD chunk swizzle (nwg=1256, %8==0):
// each XCD gets a contiguous M-chunk across all 8 N-blocks -> A-panel reuse is L2-local
// (measured FETCH 478->119 MB, R2).
__global__ __launch_bounds__(256) void gemm_big_k(const u16* __restrict__ A,
                                                  const u16* __restrict__ Bt,
                                                  u16* __restrict__ C) {
  const int h = blockIdx.y * 8 + blockIdx.x;     // hardware linear id (x-fastest)
  const int chunk = 157;                          // 1256 / 8
  const int L = (h & 7) * chunk + (h >> 3);
  const int bn = (L & 7) * 128;
  const int bm = (L >> 3) * 128;
  gemm_body<u16, false>(A, Bt, C, nullptr, N_NODES, K1P, NW, bm, bn);
}

// middle pair: hsb = xs@Ws^T, hdb = xd@Wd^T in one dispatch (z selects), grid (2,157,2)
__global__ __launch_bounds__(256) void gemm_pair_k(const u16* A0, const u16* B0, u16* C0,
                                                   const u16* A1, const u16* B1, u16* C1) {
  const u16* A = blockIdx.z ? A1 : A0;
  const u16* Bt = blockIdx.z ? B1 : B0;
  u16* C = blockIdx.z ? C1 : C0;
  gemm_body<u16, false>(A, Bt, C, nullptr, N_NODES, H_DIM, O_DIM,
                        blockIdx.y * 128, blockIdx.x * 128);
}

// final: fused = xcat @ wft^T + bf (float out)
__global__ __launch_bounds__(256) void gemm_f_k(const u16* A, const u16* Bt, float* C,
                                                const float* bias) {
  gemm_body<float, true>(A, Bt, C, bias, N_NODES, H_DIM, O_DIM,
                         blockIdx.y * 128, blockIdx.x * 128);
}

// ---------------- aggregation layer 1 ----------------
// Edge loop unrolled x4: batch the src/nrm loads, then issue all 4 row-gathers
// back-to-back before consuming -> ~4x the in-flight VMEM per wave (latency-bound fix).
__global__ __launch_bounds__(256) void agg1_k(const u16* __restrict__ h12,
                                              const int* offS, const int* srcS, const float* nrmS,
                                              const float* dinvS, const float* b1,
                                              const int* offD, const int* srcD, const float* nrmD,
                                              const float* dinvD, const float* b2,
                                              u16* __restrict__ xsd) {
  const int lane = threadIdx.x & 63;
  const int wv = threadIdx.x >> 6;
  const int i = blockIdx.x * 4 + wv;       // node (0..MPAD)
  const int g = blockIdx.y;
  if (i >= MPAD) return;
  u16* outp = xsd + ((size_t)g * MPAD + i) * H_DIM + lane * 8;
  if (i >= N_NODES) { uint4 z = {0, 0, 0, 0}; *(uint4*)outp = z; return; }

  const int* off = g ? offD : offS;
  const int* src = g ? srcD : srcS;
  const float* nrm = g ? nrmD : nrmS;
  const float* dinv = g ? dinvD : dinvS;
  const float* bias = g ? b2 : b1;
  const u16* hb = h12 + (size_t)g * H_DIM + lane * 8;

  float a[8];
  float dv = dinv[i];
  float sw = dv * dv;
  uint4 u = *(const uint4*)(hb + (size_t)i * NW);
  a[0] = sw * bf2f(u.x & 0xffff); a[1] = sw * bf2f(u.x >> 16);
  a[2] = sw * bf2f(u.y & 0xffff); a[3] = sw * bf2f(u.y >> 16);
  a[4] = sw * bf2f(u.z & 0xffff); a[5] = sw * bf2f(u.z >> 16);
  a[6] = sw * bf2f(u.w & 0xffff); a[7] = sw * bf2f(u.w >> 16);

  const int e0 = off[i], e1 = off[i + 1];
  int e = e0;
  for (; e + 4 <= e1; e += 4) {
    int ss[4]; float ww[4];
#pragma unroll
    for (int t = 0; t < 4; ++t) { ss[t] = src[e + t]; ww[t] = nrm[e + t]; }
    uint4 vv[4];
#pragma unroll
    for (int t = 0; t < 4; ++t) vv[t] = *(const uint4*)(hb + (size_t)ss[t] * NW);
#pragma unroll
    for (int t = 0; t < 4; ++t) {
      float w = ww[t]; uint4 v = vv[t];
      a[0] += w * bf2f(v.x & 0xffff); a[1] += w * bf2f(v.x >> 16);
      a[2] += w * bf2f(v.y & 0xffff); a[3] += w * bf2f(v.y >> 16);
      a[4] += w * bf2f(v.z & 0xffff); a[5] += w * bf2f(v.z >> 16);
      a[6] += w * bf2f(v.w & 0xffff); a[7] += w * bf2f(v.w >> 16);
    }
  }
  for (; e < e1; ++e) {
    int s = src[e];
    float w = nrm[e];
    uint4 v = *(const uint4*)(hb + (size_t)s * NW);
    a[0] += w * bf2f(v.x & 0xffff); a[1] += w * bf2f(v.x >> 16);
    a[2] += w * bf2f(v.y & 0xffff); a[3] += w * bf2f(v.y >> 16);
    a[4] += w * bf2f(v.z & 0xffff); a[5] += w * bf2f(v.z >> 16);
    a[6] += w * bf2f(v.w & 0xffff); a[7] += w * bf2f(v.w >> 16);
  }
  float4 bA = *(const float4*)(bias + lane * 8);
  float4 bB = *(const float4*)(bias + lane * 8 + 4);
  a[0] = fmaxf(a[0] + bA.x, 0.f); a[1] = fmaxf(a[1] + bA.y, 0.f);
  a[2] = fmaxf(a[2] + bA.z, 0.f); a[3] = fmaxf(a[3] + bA.w, 0.f);
  a[4] = fmaxf(a[4] + bB.x, 0.f); a[5] = fmaxf(a[5] + bB.y, 0.f);
  a[6] = fmaxf(a[6] + bB.z, 0.f); a[7] = fmaxf(a[7] + bB.w, 0.f);
  uint4 o;
  o.x = f2bf(a[0]) | ((unsigned)f2bf(a[1]) << 16);
  o.y = f2bf(a[2]) | ((unsigned)f2bf(a[3]) << 16);
  o.z = f2bf(a[4]) | ((unsigned)f2bf(a[5]) << 16);
  o.w = f2bf(a[6]) | ((unsigned)f2bf(a[7]) << 16);
  *(uint4*)outp = o;
}

// ---------------- aggregation layer 2 ----------------
__global__ __launch_bounds__(256) void agg2_k(const u16* __restrict__ hsb, const u16* __restrict__ hdb,
                                              const int* offS, const int* srcS, const float* nrmS,
                                              const float* dinvS, const float* bs,
                                              const int* offD, const int* srcD, const float* nrmD,
                                              const float* dinvD, const float* bd,
                                              float* __restrict__ outF, u16* __restrict__ xcat) {
  const int lane = threadIdx.x & 63;
  const int wv = threadIdx.x >> 6;
  const int i = blockIdx.x * 4 + wv;
  const int g = blockIdx.y;
  if (i >= MPAD) return;
  u16* oc = xcat + (size_t)i * H_DIM + (size_t)g * O_DIM + lane * 4;
  if (i >= N_NODES) { uint2 z = {0, 0}; *(uint2*)oc = z; return; }

  const u16* h = g ? hdb : hsb;
  const int* off = g ? offD : offS;
  const int* src = g ? srcD : srcS;
  const float* nrm = g ? nrmD : nrmS;
  const float* dinv = g ? dinvD : dinvS;
  const float* bias = g ? bd : bs;
  const u16* hb = h + lane * 4;

  float a[4];
  float dv = dinv[i];
  float sw = dv * dv;
  uint2 u = *(const uint2*)(hb + (size_t)i * O_DIM);
  a[0] = sw * bf2f(u.x & 0xffff); a[1] = sw * bf2f(u.x >> 16);
  a[2] = sw * bf2f(u.y & 0xffff); a[3] = sw * bf2f(u.y >> 16);

  const int e0 = off[i], e1 = off[i + 1];
  int e = e0;
  for (; e + 8 <= e1; e += 8) {
    int ss[8]; float ww[8];
#pragma unroll
    for (int t = 0; t < 8; ++t) { ss[t] = src[e + t]; ww[t] = nrm[e + t]; }
    uint2 vv[8];
#pragma unroll
    for (int t = 0; t < 8; ++t) vv[t] = *(const uint2*)(hb + (size_t)ss[t] * O_DIM);
#pragma unroll
    for (int t = 0; t < 8; ++t) {
      float w = ww[t]; uint2 v = vv[t];
      a[0] += w * bf2f(v.x & 0xffff); a[1] += w * bf2f(v.x >> 16);
      a[2] += w * bf2f(v.y & 0xffff); a[3] += w * bf2f(v.y >> 16);
    }
  }
  for (; e < e1; ++e) {
    int s = src[e];
    float w = nrm[e];
    uint2 v = *(const uint2*)(hb + (size_t)s * O_DIM);
    a[0] += w * bf2f(v.x & 0xffff); a[1] += w * bf2f(v.x >> 16);
    a[2] += w * bf2f(v.y & 0xffff); a[3] += w * bf2f(v.y >> 16);
  }
  float4 bb = *(const float4*)(bias + lane * 4);
  a[0] += bb.x; a[1] += bb.y; a[2] += bb.z; a[3] += bb.w;

  float4 fo = {a[0], a[1], a[2], a[3]};
  *(float4*)(outF + (size_t)g * N_NODES * O_DIM + (size_t)i * O_DIM + lane * 4) = fo;
  uint2 o;
  o.x = f2bf(a[0]) | ((unsigned)f2bf(a[1]) << 16);
  o.y = f2bf(a[2]) | ((unsigned)f2bf(a[3]) << 16);
  *(uint2*)oc = o;
}

// ---------------- launch ----------------
extern "C" void kernel_launch(void* const* d_in, const int* in_sizes, int n_in,
                              void* d_out, int out_size, void* d_ws, size_t ws_size,
                              hipStream_t stream) {
  const float* x = (const float*)d_in[0];
  const int* eiS = (const int*)d_in[1];
  const float* ewS = (const float*)d_in[2];
  const int* eiD = (const int*)d_in[3];
  const float* ewD = (const float*)d_in[4];
  const float* W1 = (const float*)d_in[5];
  const float* b1 = (const float*)d_in[6];
  const float* W2 = (const float*)d_in[7];
  const float* b2 = (const float*)d_in[8];
  const float* Ws = (const float*)d_in[9];
  const float* bs = (const float*)d_in[10];
  const float* Wd = (const float*)d_in[11];
  const float* bd = (const float*)d_in[12];
  const float* Wf = (const float*)d_in[13];
  const float* bf_ = (const float*)d_in[14];
  float* out = (float*)d_out;

  char* p = (char*)d_ws;
  auto alloc = [&](size_t n) -> char* { char* r = p; p += (n + 255) & ~(size_t)255; return r; };

  u16* xb    = (u16*)alloc((size_t)MPAD * K1P * 2);
  u16* w12t  = (u16*)alloc((size_t)NW * K1P * 2);
  u16* h12   = (u16*)alloc((size_t)N_NODES * NW * 2);
  u16* xsd   = (u16*)alloc((size_t)2 * MPAD * H_DIM * 2);
  u16* hsb   = (u16*)alloc((size_t)N_NODES * O_DIM * 2);
  u16* hdb   = (u16*)alloc((size_t)N_NODES * O_DIM * 2);
  u16* xcat  = (u16*)alloc((size_t)MPAD * H_DIM * 2);
  u16* wst   = (u16*)alloc((size_t)O_DIM * H_DIM * 2);
  u16* wdt   = (u16*)alloc((size_t)O_DIM * H_DIM * 2);
  u16* wft   = (u16*)alloc((size_t)O_DIM * H_DIM * 2);
  float* degS = (float*)alloc((size_t)N_NODES * 4);
  float* degD = (float*)alloc((size_t)N_NODES * 4);
  float* dinvS = (float*)alloc((size_t)N_NODES * 4);
  float* dinvD = (float*)alloc((size_t)N_NODES * 4);
  int* cntS = (int*)alloc((size_t)N_NODES * 4);
  int* cntD = (int*)alloc((size_t)N_NODES * 4);
  int* offS = (int*)alloc((size_t)(N_NODES + 1) * 4);
  int* offD = (int*)alloc((size_t)(N_NODES + 1) * 4);
  int* curS = (int*)alloc((size_t)(N_NODES + 1) * 4);
  int* curD = (int*)alloc((size_t)(N_NODES + 1) * 4);
  int* ssrcS = (int*)alloc((size_t)E_EDGES * 4);
  int* ssrcD = (int*)alloc((size_t)E_EDGES * 4);
  float* snrmS = (float*)alloc((size_t)E_EDGES * 4);
  float* snrmD = (float*)alloc((size_t)E_EDGES * 4);

  const int gN = (N_NODES + 255) / 256;     // 79
  const int gE = (E_EDGES + 255) / 256;     // 2500

  deg_init_k<<<gN, 256, 0, stream>>>(degS, degD, cntS, cntD);
  deg_accum_k<<<gE, 256, 0, stream>>>(eiS, ewS, eiD, ewD, degS, degD, cntS, cntD);
  dinv_k<<<gN, 256, 0, stream>>>(degS, degD, dinvS, dinvD);
  scan_k<<<2, 1024, 0, stream>>>(cntS, offS, curS, cntD, offD, curD);
  scatter_k<<<gE, 256, 0, stream>>>(eiS, ewS, dinvS, curS, ssrcS, snrmS,
                                    eiD, ewD, dinvD, curD, ssrcD, snrmD);

  conv_x_k<<<MPAD, 256, 0, stream>>>(x, xb);
  conv_w12_k<<<dim3(47, 16), 256, 0, stream>>>(W1, W2, w12t);
  conv_wsm_k<<<dim3(8, 4, 3), 256, 0, stream>>>(Ws, Wd, Wf, wst, wdt, wft);

  // h12 = xb @ w12t^T  [20000 x 1024]  (proven split path, XCD-swizzled)
  gemm_big_k<<<dim3(8, 157), 256, 0, stream>>>(xb, w12t, h12);

  agg1_k<<<dim3(MPAD / 4, 2), 256, 0, stream>>>(h12, offS, ssrcS, snrmS, dinvS, b1,
                                                offD, ssrcD, snrmD, dinvD, b2, xsd);

  // hsb = xs @ Ws^T and hdb = xd @ Wd^T in one dispatch (628 blocks)
  gemm_pair_k<<<dim3(2, 157, 2), 256, 0, stream>>>(xsd, wst, hsb,
                                                   xsd + (size_t)MPAD * H_DIM, wdt, hdb);

  agg2_k<<<dim3(MPAD / 4, 2), 256, 0, stream>>>(hsb, hdb, offS, ssrcS, snrmS, dinvS, bs,
                                                offD, ssrcD, snrmD, dinvD, bd, out, xcat);

  // fused = xcat @ wft^T + bf  -> d_out[2*N*O ..]
  gemm_f_k<<<dim3(2, 157), 256, 0, stream>>>(xcat, wft, out + (size_t)2 * N_NODES * O_DIM, bf_);
}

// Round 7
// 1022.485 us; speedup vs baseline: 1.1558x; 1.0290x over previous
//
#include <hip/hip_runtime.h>
#include <cstdint>
#include <cstddef>

typedef unsigned short u16;
typedef __bf16 bf16x8 __attribute__((ext_vector_type(8)));
typedef float f32x4 __attribute__((ext_vector_type(4)));

#define N_NODES 20000
#define MPAD    20096      // 157 * 128
#define E_EDGES 640000
#define K1      3000
#define K1P     3008       // 47 * 64
#define H_DIM   512
#define NW      1024       // W1|W2 fused width
#define O_DIM   256

__device__ __forceinline__ float bf2f(unsigned int hi) {
  union { unsigned int u; float f; } v; v.u = hi << 16; return v.f;
}
__device__ __forceinline__ u16 f2bf(float f) {
  union { float f; unsigned int u; } v; v.f = f;
  unsigned int u = v.u;
  return (u16)((u + 0x7fffu + ((u >> 16) & 1u)) >> 16);
}

__device__ __forceinline__ void gl2lds16(const void* g, void* l) {
  __builtin_amdgcn_global_load_lds((const __attribute__((address_space(1))) void*)g,
                                   (__attribute__((address_space(3))) void*)l, 16, 0, 0);
}

// ---------------- edge preprocessing ----------------
__global__ __launch_bounds__(256) void deg_init_k(float* degS, float* degD, int* cntS, int* cntD) {
  int i = blockIdx.x * 256 + threadIdx.x;
  if (i < N_NODES) { degS[i] = 1.0f; degD[i] = 1.0f; cntS[i] = 0; cntD[i] = 0; }
}

// Captures the within-bucket position (atomicAdd old value) -> epos, so scatter_k needs
// NO atomics (its atomicAdd on cur was a redundant second pass over the same counters).
__global__ __launch_bounds__(256) void deg_accum_k(const int* eiS, const float* ewS,
                                                   const int* eiD, const float* ewD,
                                                   float* degS, float* degD, int* cntS, int* cntD,
                                                   int* eposS, int* eposD) {
  int e = blockIdx.x * 256 + threadIdx.x;
  if (e < E_EDGES) {
    int cs = eiS[E_EDGES + e];
    atomicAdd(&degS[cs], ewS[e]);
    eposS[e] = atomicAdd(&cntS[cs], 1);
    int cd = eiD[E_EDGES + e];
    atomicAdd(&degD[cd], ewD[e]);
    eposD[e] = atomicAdd(&cntD[cd], 1);
  }
}

// scan v2: LDS-staged.  Old version read cnt[t*20+j] (stride-20 UNCOALESCED global) on only
// 2 CUs -> latency-bound.  Now: coalesced stride-1024 global loads into LDS (dynamic, 84KB),
// chunk-scan in LDS, coalesced stores.  dinv (rsqrt) fused in (one launch removed).
__global__ __launch_bounds__(1024) void scan_k(const int* cntS, int* offS,
                                               const float* degS, float* dinvS,
                                               const int* cntD, int* offD,
                                               const float* degD, float* dinvD) {
  extern __shared__ int lds[];           // [0..1023] sums, [1024..21023] lcnt
  int* sums = lds;
  int* lcnt = lds + 1024;
  const int* cnt = blockIdx.x ? cntD : cntS;
  int* off = blockIdx.x ? offD : offS;
  const float* deg = blockIdx.x ? degD : degS;
  float* dinv = blockIdx.x ? dinvD : dinvS;
  const int t = threadIdx.x;

  for (int idx = t; idx < N_NODES; idx += 1024) {
    lcnt[idx] = cnt[idx];
    dinv[idx] = rsqrtf(deg[idx]);
  }
  __syncthreads();

  const int CH = 20;
  const int base = t * CH;
  int s = 0;
#pragma unroll
  for (int j = 0; j < CH; ++j) { int idx = base + j; if (idx < N_NODES) s += lcnt[idx]; }
  sums[t] = s;
  __syncthreads();
  for (int d = 1; d < 1024; d <<= 1) {
    int v = (t >= d) ? sums[t - d] : 0;
    __syncthreads();
    sums[t] += v;
    __syncthreads();
  }
  int run = sums[t] - s;                 // exclusive prefix of this chunk
#pragma unroll
  for (int j = 0; j < CH; ++j) {
    int idx = base + j;
    if (idx < N_NODES) { int c = lcnt[idx]; lcnt[idx] = run; run += c; }
  }
  __syncthreads();
  for (int idx = t; idx < N_NODES; idx += 1024) off[idx] = lcnt[idx];
  if (t == 1023) off[N_NODES] = run;     // = sums[1023] = total edge count
}

// atomic-free scatter: pos = off[c] + epos[e]  (bijective within each bucket by construction)
__global__ __launch_bounds__(256) void scatter_k(const int* eiS, const float* ewS, const float* dinvS,
                                                 const int* offS, const int* eposS,
                                                 int* ssrcS, float* snrmS,
                                                 const int* eiD, const float* ewD, const float* dinvD,
                                                 const int* offD, const int* eposD,
                                                 int* ssrcD, float* snrmD) {
  int e = blockIdx.x * 256 + threadIdx.x;
  if (e < E_EDGES) {
    {
      int r = eiS[e], c = eiS[E_EDGES + e];
      int pos = offS[c] + eposS[e];
      ssrcS[pos] = r;
      snrmS[pos] = dinvS[r] * ewS[e] * dinvS[c];
    }
    {
      int r = eiD[e], c = eiD[E_EDGES + e];
      int pos = offD[c] + eposD[e];
      ssrcD[pos] = r;
      snrmD[pos] = dinvD[r] * ewD[e] * dinvD[c];
    }
  }
}

// ---------------- conversions ----------------
// x [20000][3000] f32 -> xb [MPAD][K1P] bf16 (zero-padded).  3000 = 375*8 exactly.
// (R3-R5 tried fusing this into the GEMM three ways; all lost to this split because the
// bf16 global_load_lds staging path is what makes the 170us GEMM work.  Keep split.)
__global__ __launch_bounds__(256) void conv_x_k(const float* __restrict__ x, u16* __restrict__ xb) {
  const int row = blockIdx.x;
  for (int c = threadIdx.x; c < 376; c += 256) {
    uint4 o = {0, 0, 0, 0};
    if (row < N_NODES && c < 375) {
      const float4* p = (const float4*)(x + (size_t)row * K1 + (size_t)c * 8);
      float4 v0 = p[0], v1 = p[1];
      o.x = f2bf(v0.x) | ((unsigned)f2bf(v0.y) << 16);
      o.y = f2bf(v0.z) | ((unsigned)f2bf(v0.w) << 16);
      o.z = f2bf(v1.x) | ((unsigned)f2bf(v1.y) << 16);
      o.w = f2bf(v1.z) | ((unsigned)f2bf(v1.w) << 16);
    }
    *(uint4*)(xb + (size_t)row * K1P + (size_t)c * 8) = o;
  }
}

// W1,W2 [3000][512] -> w12t [1024][3008] bf16 (transposed, padded), LDS-tiled 64x64
__global__ __launch_bounds__(256) void conv_w12_k(const float* __restrict__ W1,
                                                  const float* __restrict__ W2,
                                                  u16* __restrict__ w12t) {
  __shared__ float t[64][65];
  const int kb = blockIdx.x;           // 0..46
  const int nb = blockIdx.y;           // 0..15
  const int n0 = nb * 64;
  const float* W = (n0 < H_DIM) ? W1 : W2;
  const int nn0 = n0 & (H_DIM - 1);
  const int k0 = kb * 64;
  const int tc = threadIdx.x & 63;
  const int tr4 = threadIdx.x >> 6;    // 0..3
#pragma unroll
  for (int rr = 0; rr < 16; ++rr) {
    int r = tr4 * 16 + rr;
    int k = k0 + r;
    t[r][tc] = (k < K1) ? W[(size_t)k * H_DIM + nn0 + tc] : 0.f;
  }
  __syncthreads();
#pragma unroll
  for (int rr = 0; rr < 16; ++rr) {
    int n = tr4 * 16 + rr;
    w12t[(size_t)(n0 + n) * K1P + k0 + tc] = f2bf(t[tc][n]);
  }
}

// Ws/Wd/Wf [512][256] -> [256][512] bf16, LDS-tiled 64x64
__global__ __launch_bounds__(256) void conv_wsm_k(const float* Ws, const float* Wd, const float* Wf,
                                                  u16* wst, u16* wdt, u16* wft) {
  __shared__ float t[64][65];
  const int which = blockIdx.z;
  const float* W = (which == 0) ? Ws : (which == 1) ? Wd : Wf;
  u16* o = (which == 0) ? wst : (which == 1) ? wdt : wft;
  const int k0 = blockIdx.x * 64;      // 0..448
  const int n0 = blockIdx.y * 64;      // 0..192
  const int tc = threadIdx.x & 63;
  const int tr4 = threadIdx.x >> 6;
#pragma unroll
  for (int rr = 0; rr < 16; ++rr) {
    int r = tr4 * 16 + rr;
    t[r][tc] = W[(size_t)(k0 + r) * O_DIM + n0 + tc];
  }
  __syncthreads();
#pragma unroll
  for (int rr = 0; rr < 16; ++rr) {
    int n = tr4 * 16 + rr;
    o[(size_t)(n0 + n) * H_DIM + k0 + tc] = f2bf(t[tc][n]);
  }
}

// ---------------- shared GEMM body: C[M,N] = A[M,K] * Bt[N,K]^T (bf16 in, fp32 acc) --------
// LDS layout: row-major [128][64] u16 with XOR granule swizzle: physical 16B-granule p of
// row r holds logical granule p ^ (r&7).  Staging picks global granule (tid&7)^((tid>>3)&7)
// so the wave-uniform global_load_lds dest (base + lane*16B) lands each granule at its
// swizzled position.  Fragment ds_read_b128 then hits 8 distinct bank-quads per 8-lane
// phase group -> conflict-free (measured 0 SQ_LDS_BANK_CONFLICT).
template <typename CT, bool BIAS>
__device__ __forceinline__ void gemm_body(const u16* __restrict__ A, const u16* __restrict__ Bt,
                                          CT* __restrict__ C, const float* __restrict__ bias,
                                          int Mreal, int K, int ldc, int bm, int bn) {
  __shared__ alignas(16) u16 As[128 * 64];
  __shared__ alignas(16) u16 Bs[128 * 64];
  const int tid = threadIdx.x;
  const int lane = tid & 63;
  const int wv = tid >> 6;

  const int wm = (wv >> 1) << 6;
  const int wn = (wv & 1) << 6;
  const int frow = lane & 15;
  const int q = lane >> 4;             // logical granule base (0..3)
  const int r7 = lane & 7;             // row&7 for all fragment rows this lane touches

  const int srow = tid >> 3;           // 0..31
  const int sgr = ((tid & 7) ^ ((tid >> 3) & 7)) << 3;   // swizzled granule * 8 u16
  const u16* ga = A + (size_t)(bm + srow) * K + sgr;
  const u16* gb = Bt + (size_t)(bn + srow) * K + sgr;
  u16* la = &As[wv * 512];
  u16* lb = &Bs[wv * 512];

  f32x4 acc[4][4] = {};

  for (int k0 = 0; k0 < K; k0 += 64) {
#pragma unroll
    for (int r = 0; r < 4; ++r) {
      gl2lds16(ga + (size_t)(r * 32) * K + k0, la + r * 2048);
      gl2lds16(gb + (size_t)(r * 32) * K + k0, lb + r * 2048);
    }
    __syncthreads();
#pragma unroll
    for (int ks = 0; ks < 64; ks += 32) {
      const int p = (((q + (ks >> 3)) ^ r7) << 3);   // physical u16 offset within row
      bf16x8 af[4], bv[4];
#pragma unroll
      for (int t = 0; t < 4; ++t) {
        af[t] = *(const bf16x8*)&As[(wm + t * 16 + frow) * 64 + p];
        bv[t] = *(const bf16x8*)&Bs[(wn + t * 16 + frow) * 64 + p];
      }
#pragma unroll
      for (int i = 0; i < 4; ++i)
#pragma unroll
        for (int j = 0; j < 4; ++j)
          acc[i][j] = __builtin_amdgcn_mfma_f32_16x16x32_bf16(af[i], bv[j], acc[i][j], 0, 0, 0);
    }
    __syncthreads();
  }

  // C/D layout (m89-verified): col = lane&15, row = (lane>>4)*4 + reg
  const int crow = (lane >> 4) << 2;
  const int ccol = lane & 15;
#pragma unroll
  for (int i = 0; i < 4; ++i) {
#pragma unroll
    for (int r = 0; r < 4; ++r) {
      int gr = bm + wm + i * 16 + crow + r;
      if (gr < Mreal) {
#pragma unroll
        for (int j = 0; j < 4; ++j) {
          int gc = bn + wn + j * 16 + ccol;
          float v = acc[i][j][r];
          if constexpr (BIAS) v += bias[gc];
          if constexpr (sizeof(CT) == 2) C[(size_t)gr * ldc + gc] = (CT)f2bf(v);
          else C[(size_t)gr * ldc + gc] = (CT)v;
        }
      }
    }
  }
}

// big GEMM: h12 = xb @ w12t^T [20096 x 1024], XCD chunk swizzle (nwg=1256, %8==0):
// each XCD gets a contiguous M-chunk across all 8 N-blocks -> A-panel reuse is L2-local
// (measured FETCH 478->117 MB).
__global__ __launch_bounds__(256) void gemm_big_k(const u16* __restrict__ A,
                                                  const u16* __restrict__ Bt,
                                                  u16* __restrict__ C) {
  const int h = blockIdx.y * 8 + blockIdx.x;     // hardware linear id (x-fastest)
  const int chunk = 157;                          // 1256 / 8
  const int L = (h & 7) * chunk + (h >> 3);
  const int bn = (L & 7) * 128;
  const int bm = (L >> 3) * 128;
  gemm_body<u16, false>(A, Bt, C, nullptr, N_NODES, K1P, NW, bm, bn);
}

// middle pair: hsb = xs@Ws^T, hdb = xd@Wd^T in one dispatch (z selects), grid (2,157,2)
__global__ __launch_bounds__(256) void gemm_pair_k(const u16* A0, const u16* B0, u16* C0,
                                                   const u16* A1, const u16* B1, u16* C1) {
  const u16* A = blockIdx.z ? A1 : A0;
  const u16* Bt = blockIdx.z ? B1 : B0;
  u16* C = blockIdx.z ? C1 : C0;
  gemm_body<u16, false>(A, Bt, C, nullptr, N_NODES, H_DIM, O_DIM,
                        blockIdx.y * 128, blockIdx.x * 128);
}

// final: fused = xcat @ wft^T + bf (float out)
__global__ __launch_bounds__(256) void gemm_f_k(const u16* A, const u16* Bt, float* C,
                                                const float* bias) {
  gemm_body<float, true>(A, Bt, C, bias, N_NODES, H_DIM, O_DIM,
                         blockIdx.y * 128, blockIdx.x * 128);
}

// ---------------- aggregation layer 1 ----------------
// Edge loop unrolled x6 (up from x4): 6 row-gathers in flight per wave, ~60 VGPR (stays
// under the 64-VGPR / 32-wave occupancy tier).
__global__ __launch_bounds__(256) void agg1_k(const u16* __restrict__ h12,
                                              const int* offS, const int* srcS, const float* nrmS,
                                              const float* dinvS, const float* b1,
                                              const int* offD, const int* srcD, const float* nrmD,
                                              const float* dinvD, const float* b2,
                                              u16* __restrict__ xsd) {
  const int lane = threadIdx.x & 63;
  const int wv = threadIdx.x >> 6;
  const int i = blockIdx.x * 4 + wv;       // node (0..MPAD)
  const int g = blockIdx.y;
  if (i >= MPAD) return;
  u16* outp = xsd + ((size_t)g * MPAD + i) * H_DIM + lane * 8;
  if (i >= N_NODES) { uint4 z = {0, 0, 0, 0}; *(uint4*)outp = z; return; }

  const int* off = g ? offD : offS;
  const int* src = g ? srcD : srcS;
  const float* nrm = g ? nrmD : nrmS;
  const float* dinv = g ? dinvD : dinvS;
  const float* bias = g ? b2 : b1;
  const u16* hb = h12 + (size_t)g * H_DIM + lane * 8;

  float a[8];
  float dv = dinv[i];
  float sw = dv * dv;
  uint4 u = *(const uint4*)(hb + (size_t)i * NW);
  a[0] = sw * bf2f(u.x & 0xffff); a[1] = sw * bf2f(u.x >> 16);
  a[2] = sw * bf2f(u.y & 0xffff); a[3] = sw * bf2f(u.y >> 16);
  a[4] = sw * bf2f(u.z & 0xffff); a[5] = sw * bf2f(u.z >> 16);
  a[6] = sw * bf2f(u.w & 0xffff); a[7] = sw * bf2f(u.w >> 16);

  const int e0 = off[i], e1 = off[i + 1];
  int e = e0;
  for (; e + 6 <= e1; e += 6) {
    int ss[6]; float ww[6];
#pragma unroll
    for (int t = 0; t < 6; ++t) { ss[t] = src[e + t]; ww[t] = nrm[e + t]; }
    uint4 vv[6];
#pragma unroll
    for (int t = 0; t < 6; ++t) vv[t] = *(const uint4*)(hb + (size_t)ss[t] * NW);
#pragma unroll
    for (int t = 0; t < 6; ++t) {
      float w = ww[t]; uint4 v = vv[t];
      a[0] += w * bf2f(v.x & 0xffff); a[1] += w * bf2f(v.x >> 16);
      a[2] += w * bf2f(v.y & 0xffff); a[3] += w * bf2f(v.y >> 16);
      a[4] += w * bf2f(v.z & 0xffff); a[5] += w * bf2f(v.z >> 16);
      a[6] += w * bf2f(v.w & 0xffff); a[7] += w * bf2f(v.w >> 16);
    }
  }
  for (; e < e1; ++e) {
    int s = src[e];
    float w = nrm[e];
    uint4 v = *(const uint4*)(hb + (size_t)s * NW);
    a[0] += w * bf2f(v.x & 0xffff); a[1] += w * bf2f(v.x >> 16);
    a[2] += w * bf2f(v.y & 0xffff); a[3] += w * bf2f(v.y >> 16);
    a[4] += w * bf2f(v.z & 0xffff); a[5] += w * bf2f(v.z >> 16);
    a[6] += w * bf2f(v.w & 0xffff); a[7] += w * bf2f(v.w >> 16);
  }
  float4 bA = *(const float4*)(bias + lane * 8);
  float4 bB = *(const float4*)(bias + lane * 8 + 4);
  a[0] = fmaxf(a[0] + bA.x, 0.f); a[1] = fmaxf(a[1] + bA.y, 0.f);
  a[2] = fmaxf(a[2] + bA.z, 0.f); a[3] = fmaxf(a[3] + bA.w, 0.f);
  a[4] = fmaxf(a[4] + bB.x, 0.f); a[5] = fmaxf(a[5] + bB.y, 0.f);
  a[6] = fmaxf(a[6] + bB.z, 0.f); a[7] = fmaxf(a[7] + bB.w, 0.f);
  uint4 o;
  o.x = f2bf(a[0]) | ((unsigned)f2bf(a[1]) << 16);
  o.y = f2bf(a[2]) | ((unsigned)f2bf(a[3]) << 16);
  o.z = f2bf(a[4]) | ((unsigned)f2bf(a[5]) << 16);
  o.w = f2bf(a[6]) | ((unsigned)f2bf(a[7]) << 16);
  *(uint4*)outp = o;
}

// ---------------- aggregation layer 2 ----------------
__global__ __launch_bounds__(256) void agg2_k(const u16* __restrict__ hsb, const u16* __restrict__ hdb,
                                              const int* offS, const int* srcS, const float* nrmS,
                                              const float* dinvS, const float* bs,
                                              const int* offD, const int* srcD, const float* nrmD,
                                              const float* dinvD, const float* bd,
                                              float* __restrict__ outF, u16* __restrict__ xcat) {
  const int lane = threadIdx.x & 63;
  const int wv = threadIdx.x >> 6;
  const int i = blockIdx.x * 4 + wv;
  const int g = blockIdx.y;
  if (i >= MPAD) return;
  u16* oc = xcat + (size_t)i * H_DIM + (size_t)g * O_DIM + lane * 4;
  if (i >= N_NODES) { uint2 z = {0, 0}; *(uint2*)oc = z; return; }

  const u16* h = g ? hdb : hsb;
  const int* off = g ? offD : offS;
  const int* src = g ? srcD : srcS;
  const float* nrm = g ? nrmD : nrmS;
  const float* dinv = g ? dinvD : dinvS;
  const float* bias = g ? bd : bs;
  const u16* hb = h + lane * 4;

  float a[4];
  float dv = dinv[i];
  float sw = dv * dv;
  uint2 u = *(const uint2*)(hb + (size_t)i * O_DIM);
  a[0] = sw * bf2f(u.x & 0xffff); a[1] = sw * bf2f(u.x >> 16);
  a[2] = sw * bf2f(u.y & 0xffff); a[3] = sw * bf2f(u.y >> 16);

  const int e0 = off[i], e1 = off[i + 1];
  int e = e0;
  for (; e + 8 <= e1; e += 8) {
    int ss[8]; float ww[8];
#pragma unroll
    for (int t = 0; t < 8; ++t) { ss[t] = src[e + t]; ww[t] = nrm[e + t]; }
    uint2 vv[8];
#pragma unroll
    for (int t = 0; t < 8; ++t) vv[t] = *(const uint2*)(hb + (size_t)ss[t] * O_DIM);
#pragma unroll
    for (int t = 0; t < 8; ++t) {
      float w = ww[t]; uint2 v = vv[t];
      a[0] += w * bf2f(v.x & 0xffff); a[1] += w * bf2f(v.x >> 16);
      a[2] += w * bf2f(v.y & 0xffff); a[3] += w * bf2f(v.y >> 16);
    }
  }
  for (; e < e1; ++e) {
    int s = src[e];
    float w = nrm[e];
    uint2 v = *(const uint2*)(hb + (size_t)s * O_DIM);
    a[0] += w * bf2f(v.x & 0xffff); a[1] += w * bf2f(v.x >> 16);
    a[2] += w * bf2f(v.y & 0xffff); a[3] += w * bf2f(v.y >> 16);
  }
  float4 bb = *(const float4*)(bias + lane * 4);
  a[0] += bb.x; a[1] += bb.y; a[2] += bb.z; a[3] += bb.w;

  float4 fo = {a[0], a[1], a[2], a[3]};
  *(float4*)(outF + (size_t)g * N_NODES * O_DIM + (size_t)i * O_DIM + lane * 4) = fo;
  uint2 o;
  o.x = f2bf(a[0]) | ((unsigned)f2bf(a[1]) << 16);
  o.y = f2bf(a[2]) | ((unsigned)f2bf(a[3]) << 16);
  *(uint2*)oc = o;
}

// ---------------- launch ----------------
extern "C" void kernel_launch(void* const* d_in, const int* in_sizes, int n_in,
                              void* d_out, int out_size, void* d_ws, size_t ws_size,
                              hipStream_t stream) {
  const float* x = (const float*)d_in[0];
  const int* eiS = (const int*)d_in[1];
  const float* ewS = (const float*)d_in[2];
  const int* eiD = (const int*)d_in[3];
  const float* ewD = (const float*)d_in[4];
  const float* W1 = (const float*)d_in[5];
  const float* b1 = (const float*)d_in[6];
  const float* W2 = (const float*)d_in[7];
  const float* b2 = (const float*)d_in[8];
  const float* Ws = (const float*)d_in[9];
  const float* bs = (const float*)d_in[10];
  const float* Wd = (const float*)d_in[11];
  const float* bd = (const float*)d_in[12];
  const float* Wf = (const float*)d_in[13];
  const float* bf_ = (const float*)d_in[14];
  float* out = (float*)d_out;

  char* p = (char*)d_ws;
  auto alloc = [&](size_t n) -> char* { char* r = p; p += (n + 255) & ~(size_t)255; return r; };

  u16* xb    = (u16*)alloc((size_t)MPAD * K1P * 2);
  u16* w12t  = (u16*)alloc((size_t)NW * K1P * 2);
  u16* h12   = (u16*)alloc((size_t)N_NODES * NW * 2);
  u16* xsd   = (u16*)alloc((size_t)2 * MPAD * H_DIM * 2);
  u16* hsb   = (u16*)alloc((size_t)N_NODES * O_DIM * 2);
  u16* hdb   = (u16*)alloc((size_t)N_NODES * O_DIM * 2);
  u16* xcat  = (u16*)alloc((size_t)MPAD * H_DIM * 2);
  u16* wst   = (u16*)alloc((size_t)O_DIM * H_DIM * 2);
  u16* wdt   = (u16*)alloc((size_t)O_DIM * H_DIM * 2);
  u16* wft   = (u16*)alloc((size_t)O_DIM * H_DIM * 2);
  float* degS = (float*)alloc((size_t)N_NODES * 4);
  float* degD = (float*)alloc((size_t)N_NODES * 4);
  float* dinvS = (float*)alloc((size_t)N_NODES * 4);
  float* dinvD = (float*)alloc((size_t)N_NODES * 4);
  int* cntS = (int*)alloc((size_t)N_NODES * 4);
  int* cntD = (int*)alloc((size_t)N_NODES * 4);
  int* offS = (int*)alloc((size_t)(N_NODES + 1) * 4);
  int* offD = (int*)alloc((size_t)(N_NODES + 1) * 4);
  int* eposS = (int*)alloc((size_t)E_EDGES * 4);
  int* eposD = (int*)alloc((size_t)E_EDGES * 4);
  int* ssrcS = (int*)alloc((size_t)E_EDGES * 4);
  int* ssrcD = (int*)alloc((size_t)E_EDGES * 4);
  float* snrmS = (float*)alloc((size_t)E_EDGES * 4);
  float* snrmD = (float*)alloc((size_t)E_EDGES * 4);

  const int gN = (N_NODES + 255) / 256;     // 79
  const int gE = (E_EDGES + 255) / 256;     // 2500

  deg_init_k<<<gN, 256, 0, stream>>>(degS, degD, cntS, cntD);
  deg_accum_k<<<gE, 256, 0, stream>>>(eiS, ewS, eiD, ewD, degS, degD, cntS, cntD, eposS, eposD);
  scan_k<<<2, 1024, (size_t)(1024 + N_NODES) * 4, stream>>>(cntS, offS, degS, dinvS,
                                                            cntD, offD, degD, dinvD);
  scatter_k<<<gE, 256, 0, stream>>>(eiS, ewS, dinvS, offS, eposS, ssrcS, snrmS,
                                    eiD, ewD, dinvD, offD, eposD, ssrcD, snrmD);

  conv_x_k<<<MPAD, 256, 0, stream>>>(x, xb);
  conv_w12_k<<<dim3(47, 16), 256, 0, stream>>>(W1, W2, w12t);
  conv_wsm_k<<<dim3(8, 4, 3), 256, 0, stream>>>(Ws, Wd, Wf, wst, wdt, wft);

  // h12 = xb @ w12t^T  [20000 x 1024]  (proven split path, XCD-swizzled)
  gemm_big_k<<<dim3(8, 157), 256, 0, stream>>>(xb, w12t, h12);

  agg1_k<<<dim3(MPAD / 4, 2), 256, 0, stream>>>(h12, offS, ssrcS, snrmS, dinvS, b1,
                                                offD, ssrcD, snrmD, dinvD, b2, xsd);

  // hsb = xs @ Ws^T and hdb = xd @ Wd^T in one dispatch (628 blocks)
  gemm_pair_k<<<dim3(2, 157, 2), 256, 0, stream>>>(xsd, wst, hsb,
                                                   xsd + (size_t)MPAD * H_DIM, wdt, hdb);

  agg2_k<<<dim3(MPAD / 4, 2), 256, 0, stream>>>(hsb, hdb, offS, ssrcS, snrmS, dinvS, bs,
                                                offD, ssrcD, snrmD, dinvD, bd, out, xcat);

  // fused = xcat @ wft^T + bf  -> d_out[2*N*O ..]
  gemm_f_k<<<dim3(2, 157), 256, 0, stream>>>(xcat, wft, out + (size_t)2 * N_NODES * O_DIM, bf_);
}

// Round 9
// 988.218 us; speedup vs baseline: 1.1959x; 1.0347x over previous
//
#include <hip/hip_runtime.h>
#include <cstdint>
#include <cstddef>

typedef unsigned short u16;
typedef __bf16 bf16x8 __attribute__((ext_vector_type(8)));
typedef float f32x4 __attribute__((ext_vector_type(4)));

#define N_NODES 20000
#define MPAD    20096      // 157 * 128
#define E_EDGES 640000
#define K1      3000
#define K1P     3008       // 47 * 64
#define H_DIM   512
#define NW      1024       // W1|W2 fused width
#define O_DIM   256

#define NB_GEMM   1256     // 8 * 157 gemm blocks in gemm_sc_k
#define NB_EDGE   2500     // ceil(E_EDGES/256)

__device__ __forceinline__ float bf2f(unsigned int hi) {
  union { unsigned int u; float f; } v; v.u = hi << 16; return v.f;
}
__device__ __forceinline__ u16 f2bf(float f) {
  union { float f; unsigned int u; } v; v.f = f;
  unsigned int u = v.u;
  return (u16)((u + 0x7fffu + ((u >> 16) & 1u)) >> 16);
}

__device__ __forceinline__ void gl2lds16(const void* g, void* l) {
  __builtin_amdgcn_global_load_lds((const __attribute__((address_space(1))) void*)g,
                                   (__attribute__((address_space(3))) void*)l, 16, 0, 0);
}

// ---------------- tiny init ----------------
__global__ __launch_bounds__(256) void deg_init_k(float* degS, float* degD, int* cntS, int* cntD) {
  int i = blockIdx.x * 256 + threadIdx.x;
  if (i < N_NODES) { degS[i] = 1.0f; degD[i] = 1.0f; cntS[i] = 0; cntD[i] = 0; }
}

// ---------------- fused pre-pass: conv_x | conv_w12 | conv_wsm | deg_accum ----------------
// All four are mutually independent; one dispatch lets the BW-bound conv_x overlap the
// atomic-latency-bound deg_accum (were ~110us serialized across 4 launches).
// Block map: [0,MPAD) conv_x row | [MPAD,+752) conv_w12 | [+96) conv_wsm | [+2500) deg_accum.
__global__ __launch_bounds__(256) void pre_k(const float* __restrict__ x, u16* __restrict__ xb,
                                             const float* __restrict__ W1, const float* __restrict__ W2,
                                             u16* __restrict__ w12t,
                                             const float* Ws, const float* Wd, const float* Wf,
                                             u16* wst, u16* wdt, u16* wft,
                                             const int* eiS, const float* ewS,
                                             const int* eiD, const float* ewD,
                                             float* degS, float* degD, int* cntS, int* cntD,
                                             int* eposS, int* eposD) {
  __shared__ float t[64][65];
  int b = blockIdx.x;

  if (b < MPAD) {                       // ---- conv_x: x row -> xb bf16 (zero-padded) ----
    const int row = b;
    for (int c = threadIdx.x; c < 376; c += 256) {
      uint4 o = {0, 0, 0, 0};
      if (row < N_NODES && c < 375) {
        const float4* p = (const float4*)(x + (size_t)row * K1 + (size_t)c * 8);
        float4 v0 = p[0], v1 = p[1];
        o.x = f2bf(v0.x) | ((unsigned)f2bf(v0.y) << 16);
        o.y = f2bf(v0.z) | ((unsigned)f2bf(v0.w) << 16);
        o.z = f2bf(v1.x) | ((unsigned)f2bf(v1.y) << 16);
        o.w = f2bf(v1.z) | ((unsigned)f2bf(v1.w) << 16);
      }
      *(uint4*)(xb + (size_t)row * K1P + (size_t)c * 8) = o;
    }
    return;
  }
  b -= MPAD;

  if (b < 752) {                        // ---- conv_w12: W1|W2 -> w12t [1024][3008] ----
    const int kb = b % 47;
    const int nb = b / 47;
    const int n0 = nb * 64;
    const float* W = (n0 < H_DIM) ? W1 : W2;
    const int nn0 = n0 & (H_DIM - 1);
    const int k0 = kb * 64;
    const int tc = threadIdx.x & 63;
    const int tr4 = threadIdx.x >> 6;
#pragma unroll
    for (int rr = 0; rr < 16; ++rr) {
      int r = tr4 * 16 + rr;
      int k = k0 + r;
      t[r][tc] = (k < K1) ? W[(size_t)k * H_DIM + nn0 + tc] : 0.f;
    }
    __syncthreads();
#pragma unroll
    for (int rr = 0; rr < 16; ++rr) {
      int n = tr4 * 16 + rr;
      w12t[(size_t)(n0 + n) * K1P + k0 + tc] = f2bf(t[tc][n]);
    }
    return;
  }
  b -= 752;

  if (b < 96) {                         // ---- conv_wsm: Ws/Wd/Wf -> [256][512] ----
    const int which = b >> 5;           // 0..2
    const int rem = b & 31;
    const float* W = (which == 0) ? Ws : (which == 1) ? Wd : Wf;
    u16* o = (which == 0) ? wst : (which == 1) ? wdt : wft;
    const int k0 = (rem & 7) * 64;
    const int n0 = (rem >> 3) * 64;
    const int tc = threadIdx.x & 63;
    const int tr4 = threadIdx.x >> 6;
#pragma unroll
    for (int rr = 0; rr < 16; ++rr) {
      int r = tr4 * 16 + rr;
      t[r][tc] = W[(size_t)(k0 + r) * O_DIM + n0 + tc];
    }
    __syncthreads();
#pragma unroll
    for (int rr = 0; rr < 16; ++rr) {
      int n = tr4 * 16 + rr;
      o[(size_t)(n0 + n) * H_DIM + k0 + tc] = f2bf(t[tc][n]);
    }
    return;
  }
  b -= 96;

  {                                     // ---- deg_accum (+ epos capture, R7) ----
    int e = b * 256 + threadIdx.x;
    if (e < E_EDGES) {
      int cs = eiS[E_EDGES + e];
      atomicAdd(&degS[cs], ewS[e]);
      eposS[e] = atomicAdd(&cntS[cs], 1);
      int cd = eiD[E_EDGES + e];
      atomicAdd(&degD[cd], ewD[e]);
      eposD[e] = atomicAdd(&cntD[cd], 1);
    }
  }
}

// scan: LDS-staged coalesced chunk-scan + fused rsqrt (R7, verified)
__global__ __launch_bounds__(1024) void scan_k(const int* cntS, int* offS,
                                               const float* degS, float* dinvS,
                                               const int* cntD, int* offD,
                                               const float* degD, float* dinvD) {
  extern __shared__ int lds[];           // [0..1023] sums, [1024..] lcnt
  int* sums = lds;
  int* lcnt = lds + 1024;
  const int* cnt = blockIdx.x ? cntD : cntS;
  int* off = blockIdx.x ? offD : offS;
  const float* deg = blockIdx.x ? degD : degS;
  float* dinv = blockIdx.x ? dinvD : dinvS;
  const int t = threadIdx.x;

  for (int idx = t; idx < N_NODES; idx += 1024) {
    lcnt[idx] = cnt[idx];
    dinv[idx] = rsqrtf(deg[idx]);
  }
  __syncthreads();

  const int CH = 20;
  const int base = t * CH;
  int s = 0;
#pragma unroll
  for (int j = 0; j < CH; ++j) { int idx = base + j; if (idx < N_NODES) s += lcnt[idx]; }
  sums[t] = s;
  __syncthreads();
  for (int d = 1; d < 1024; d <<= 1) {
    int v = (t >= d) ? sums[t - d] : 0;
    __syncthreads();
    sums[t] += v;
    __syncthreads();
  }
  int run = sums[t] - s;                 // exclusive prefix of this chunk
#pragma unroll
  for (int j = 0; j < CH; ++j) {
    int idx = base + j;
    if (idx < N_NODES) { int c = lcnt[idx]; lcnt[idx] = run; run += c; }
  }
  __syncthreads();
  for (int idx = t; idx < N_NODES; idx += 1024) off[idx] = lcnt[idx];
  if (t == 1023) off[N_NODES] = run;
}

// ---------------- shared GEMM body: C[M,N] = A[M,K] * Bt[N,K]^T (bf16 in, fp32 acc) --------
// LDS layout: row-major [128][64] u16 with XOR granule swizzle (measured 0 bank conflicts).
template <typename CT, bool BIAS>
__device__ __forceinline__ void gemm_body(const u16* __restrict__ A, const u16* __restrict__ Bt,
                                          CT* __restrict__ C, const float* __restrict__ bias,
                                          int Mreal, int K, int ldc, int bm, int bn) {
  __shared__ alignas(16) u16 As[128 * 64];
  __shared__ alignas(16) u16 Bs[128 * 64];
  const int tid = threadIdx.x;
  const int lane = tid & 63;
  const int wv = tid >> 6;

  const int wm = (wv >> 1) << 6;
  const int wn = (wv & 1) << 6;
  const int frow = lane & 15;
  const int q = lane >> 4;             // logical granule base (0..3)
  const int r7 = lane & 7;             // row&7 for all fragment rows this lane touches

  const int srow = tid >> 3;           // 0..31
  const int sgr = ((tid & 7) ^ ((tid >> 3) & 7)) << 3;   // swizzled granule * 8 u16
  const u16* ga = A + (size_t)(bm + srow) * K + sgr;
  const u16* gb = Bt + (size_t)(bn + srow) * K + sgr;
  u16* la = &As[wv * 512];
  u16* lb = &Bs[wv * 512];

  f32x4 acc[4][4] = {};

  for (int k0 = 0; k0 < K; k0 += 64) {
#pragma unroll
    for (int r = 0; r < 4; ++r) {
      gl2lds16(ga + (size_t)(r * 32) * K + k0, la + r * 2048);
      gl2lds16(gb + (size_t)(r * 32) * K + k0, lb + r * 2048);
    }
    __syncthreads();
#pragma unroll
    for (int ks = 0; ks < 64; ks += 32) {
      const int p = (((q + (ks >> 3)) ^ r7) << 3);   // physical u16 offset within row
      bf16x8 af[4], bv[4];
#pragma unroll
      for (int t = 0; t < 4; ++t) {
        af[t] = *(const bf16x8*)&As[(wm + t * 16 + frow) * 64 + p];
        bv[t] = *(const bf16x8*)&Bs[(wn + t * 16 + frow) * 64 + p];
      }
#pragma unroll
      for (int i = 0; i < 4; ++i)
#pragma unroll
        for (int j = 0; j < 4; ++j)
          acc[i][j] = __builtin_amdgcn_mfma_f32_16x16x32_bf16(af[i], bv[j], acc[i][j], 0, 0, 0);
    }
    __syncthreads();
  }

  // C/D layout (m89-verified): col = lane&15, row = (lane>>4)*4 + reg
  const int crow = (lane >> 4) << 2;
  const int ccol = lane & 15;
#pragma unroll
  for (int i = 0; i < 4; ++i) {
#pragma unroll
    for (int r = 0; r < 4; ++r) {
      int gr = bm + wm + i * 16 + crow + r;
      if (gr < Mreal) {
#pragma unroll
        for (int j = 0; j < 4; ++j) {
          int gc = bn + wn + j * 16 + ccol;
          float v = acc[i][j][r];
          if constexpr (BIAS) v += bias[gc];
          if constexpr (sizeof(CT) == 2) C[(size_t)gr * ldc + gc] = (CT)f2bf(v);
          else C[(size_t)gr * ldc + gc] = (CT)v;
        }
      }
    }
  }
}

// fused big GEMM + edge scatter.  Blocks [0,1256): h12 = xb @ w12t^T with XCD chunk swizzle
// (1D linear id == old y*8+x; scatter blocks appended AFTER so gemm ids/XCD map unchanged;
// measured FETCH 478->117 MB).  Blocks [1256,+2500): atomic-free scatter (latency/RMW-bound,
// hides under the GEMM's spare BW -- gemm uses ~940 GB/s of 6300).
__global__ __launch_bounds__(256) void gemm_sc_k(const u16* __restrict__ A,
                                                 const u16* __restrict__ Bt,
                                                 u16* __restrict__ C,
                                                 const int* eiS, const float* ewS, const float* dinvS,
                                                 const int* offS, const int* eposS,
                                                 int* ssrcS, float* snrmS,
                                                 const int* eiD, const float* ewD, const float* dinvD,
                                                 const int* offD, const int* eposD,
                                                 int* ssrcD, float* snrmD) {
  int b = blockIdx.x;
  if (b < NB_GEMM) {
    const int chunk = 157;               // 1256 / 8
    const int L = (b & 7) * chunk + (b >> 3);
    gemm_body<u16, false>(A, Bt, C, nullptr, N_NODES, K1P, NW, (L >> 3) * 128, (L & 7) * 128);
    return;
  }
  b -= NB_GEMM;
  int e = b * 256 + threadIdx.x;
  if (e < E_EDGES) {
    {
      int r = eiS[e], c = eiS[E_EDGES + e];
      int pos = offS[c] + eposS[e];
      ssrcS[pos] = r;
      snrmS[pos] = dinvS[r] * ewS[e] * dinvS[c];
    }
    {
      int r = eiD[e], c = eiD[E_EDGES + e];
      int pos = offD[c] + eposD[e];
      ssrcD[pos] = r;
      snrmD[pos] = dinvD[r] * ewD[e] * dinvD[c];
    }
  }
}

// middle pair: hsb = xs@Ws^T, hdb = xd@Wd^T in one dispatch (z selects), grid (2,157,2)
__global__ __launch_bounds__(256) void gemm_pair_k(const u16* A0, const u16* B0, u16* C0,
                                                   const u16* A1, const u16* B1, u16* C1) {
  const u16* A = blockIdx.z ? A1 : A0;
  const u16* Bt = blockIdx.z ? B1 : B0;
  u16* C = blockIdx.z ? C1 : C0;
  gemm_body<u16, false>(A, Bt, C, nullptr, N_NODES, H_DIM, O_DIM,
                        blockIdx.y * 128, blockIdx.x * 128);
}

// final: fused = xcat @ wft^T + bf (float out)
__global__ __launch_bounds__(256) void gemm_f_k(const u16* A, const u16* Bt, float* C,
                                                const float* bias) {
  gemm_body<float, true>(A, Bt, C, bias, N_NODES, H_DIM, O_DIM,
                         blockIdx.y * 128, blockIdx.x * 128);
}

// ---------------- aggregation layer 1 ----------------
// Edge loop unrolled x6: 6 row-gathers in flight per wave, stays under 64-VGPR tier.
__global__ __launch_bounds__(256) void agg1_k(const u16* __restrict__ h12,
                                              const int* offS, const int* srcS, const float* nrmS,
                                              const float* dinvS, const float* b1,
                                              const int* offD, const int* srcD, const float* nrmD,
                                              const float* dinvD, const float* b2,
                                              u16* __restrict__ xsd) {
  const int lane = threadIdx.x & 63;
  const int wv = threadIdx.x >> 6;
  const int i = blockIdx.x * 4 + wv;       // node (0..MPAD)
  const int g = blockIdx.y;
  if (i >= MPAD) return;
  u16* outp = xsd + ((size_t)g * MPAD + i) * H_DIM + lane * 8;
  if (i >= N_NODES) { uint4 z = {0, 0, 0, 0}; *(uint4*)outp = z; return; }

  const int* off = g ? offD : offS;
  const int* src = g ? srcD : srcS;
  const float* nrm = g ? nrmD : nrmS;
  const float* dinv = g ? dinvD : dinvS;
  const float* bias = g ? b2 : b1;
  const u16* hb = h12 + (size_t)g * H_DIM + lane * 8;

  float a[8];
  float dv = dinv[i];
  float sw = dv * dv;
  uint4 u = *(const uint4*)(hb + (size_t)i * NW);
  a[0] = sw * bf2f(u.x & 0xffff); a[1] = sw * bf2f(u.x >> 16);
  a[2] = sw * bf2f(u.y & 0xffff); a[3] = sw * bf2f(u.y >> 16);
  a[4] = sw * bf2f(u.z & 0xffff); a[5] = sw * bf2f(u.z >> 16);
  a[6] = sw * bf2f(u.w & 0xffff); a[7] = sw * bf2f(u.w >> 16);

  const int e0 = off[i], e1 = off[i + 1];
  int e = e0;
  for (; e + 6 <= e1; e += 6) {
    int ss[6]; float ww[6];
#pragma unroll
    for (int t = 0; t < 6; ++t) { ss[t] = src[e + t]; ww[t] = nrm[e + t]; }
    uint4 vv[6];
#pragma unroll
    for (int t = 0; t < 6; ++t) vv[t] = *(const uint4*)(hb + (size_t)ss[t] * NW);
#pragma unroll
    for (int t = 0; t < 6; ++t) {
      float w = ww[t]; uint4 v = vv[t];
      a[0] += w * bf2f(v.x & 0xffff); a[1] += w * bf2f(v.x >> 16);
      a[2] += w * bf2f(v.y & 0xffff); a[3] += w * bf2f(v.y >> 16);
      a[4] += w * bf2f(v.z & 0xffff); a[5] += w * bf2f(v.z >> 16);
      a[6] += w * bf2f(v.w & 0xffff); a[7] += w * bf2f(v.w >> 16);
    }
  }
  for (; e < e1; ++e) {
    int s = src[e];
    float w = nrm[e];
    uint4 v = *(const uint4*)(hb + (size_t)s * NW);
    a[0] += w * bf2f(v.x & 0xffff); a[1] += w * bf2f(v.x >> 16);
    a[2] += w * bf2f(v.y & 0xffff); a[3] += w * bf2f(v.y >> 16);
    a[4] += w * bf2f(v.z & 0xffff); a[5] += w * bf2f(v.z >> 16);
    a[6] += w * bf2f(v.w & 0xffff); a[7] += w * bf2f(v.w >> 16);
  }
  float4 bA = *(const float4*)(bias + lane * 8);
  float4 bB = *(const float4*)(bias + lane * 8 + 4);
  a[0] = fmaxf(a[0] + bA.x, 0.f); a[1] = fmaxf(a[1] + bA.y, 0.f);
  a[2] = fmaxf(a[2] + bA.z, 0.f); a[3] = fmaxf(a[3] + bA.w, 0.f);
  a[4] = fmaxf(a[4] + bB.x, 0.f); a[5] = fmaxf(a[5] + bB.y, 0.f);
  a[6] = fmaxf(a[6] + bB.z, 0.f); a[7] = fmaxf(a[7] + bB.w, 0.f);
  uint4 o;
  o.x = f2bf(a[0]) | ((unsigned)f2bf(a[1]) << 16);
  o.y = f2bf(a[2]) | ((unsigned)f2bf(a[3]) << 16);
  o.z = f2bf(a[4]) | ((unsigned)f2bf(a[5]) << 16);
  o.w = f2bf(a[6]) | ((unsigned)f2bf(a[7]) << 16);
  *(uint4*)outp = o;
}

// ---------------- aggregation layer 2 ----------------
__global__ __launch_bounds__(256) void agg2_k(const u16* __restrict__ hsb, const u16* __restrict__ hdb,
                                              const int* offS, const int* srcS, const float* nrmS,
                                              const float* dinvS, const float* bs,
                                              const int* offD, const int* srcD, const float* nrmD,
                                              const float* dinvD, const float* bd,
                                              float* __restrict__ outF, u16* __restrict__ xcat) {
  const int lane = threadIdx.x & 63;
  const int wv = threadIdx.x >> 6;
  const int i = blockIdx.x * 4 + wv;
  const int g = blockIdx.y;
  if (i >= MPAD) return;
  u16* oc = xcat + (size_t)i * H_DIM + (size_t)g * O_DIM + lane * 4;
  if (i >= N_NODES) { uint2 z = {0, 0}; *(uint2*)oc = z; return; }

  const u16* h = g ? hdb : hsb;
  const int* off = g ? offD : offS;
  const int* src = g ? srcD : srcS;
  const float* nrm = g ? nrmD : nrmS;
  const float* dinv = g ? dinvD : dinvS;
  const float* bias = g ? bd : bs;
  const u16* hb = h + lane * 4;

  float a[4];
  float dv = dinv[i];
  float sw = dv * dv;
  uint2 u = *(const uint2*)(hb + (size_t)i * O_DIM);
  a[0] = sw * bf2f(u.x & 0xffff); a[1] = sw * bf2f(u.x >> 16);
  a[2] = sw * bf2f(u.y & 0xffff); a[3] = sw * bf2f(u.y >> 16);

  const int e0 = off[i], e1 = off[i + 1];
  int e = e0;
  for (; e + 8 <= e1; e += 8) {
    int ss[8]; float ww[8];
#pragma unroll
    for (int t = 0; t < 8; ++t) { ss[t] = src[e + t]; ww[t] = nrm[e + t]; }
    uint2 vv[8];
#pragma unroll
    for (int t = 0; t < 8; ++t) vv[t] = *(const uint2*)(hb + (size_t)ss[t] * O_DIM);
#pragma unroll
    for (int t = 0; t < 8; ++t) {
      float w = ww[t]; uint2 v = vv[t];
      a[0] += w * bf2f(v.x & 0xffff); a[1] += w * bf2f(v.x >> 16);
      a[2] += w * bf2f(v.y & 0xffff); a[3] += w * bf2f(v.y >> 16);
    }
  }
  for (; e < e1; ++e) {
    int s = src[e];
    float w = nrm[e];
    uint2 v = *(const uint2*)(hb + (size_t)s * O_DIM);
    a[0] += w * bf2f(v.x & 0xffff); a[1] += w * bf2f(v.x >> 16);
    a[2] += w * bf2f(v.y & 0xffff); a[3] += w * bf2f(v.y >> 16);
  }
  float4 bb = *(const float4*)(bias + lane * 4);
  a[0] += bb.x; a[1] += bb.y; a[2] += bb.z; a[3] += bb.w;

  float4 fo = {a[0], a[1], a[2], a[3]};
  *(float4*)(outF + (size_t)g * N_NODES * O_DIM + (size_t)i * O_DIM + lane * 4) = fo;
  uint2 o;
  o.x = f2bf(a[0]) | ((unsigned)f2bf(a[1]) << 16);
  o.y = f2bf(a[2]) | ((unsigned)f2bf(a[3]) << 16);
  *(uint2*)oc = o;
}

// ---------------- launch ----------------
extern "C" void kernel_launch(void* const* d_in, const int* in_sizes, int n_in,
                              void* d_out, int out_size, void* d_ws, size_t ws_size,
                              hipStream_t stream) {
  const float* x = (const float*)d_in[0];
  const int* eiS = (const int*)d_in[1];
  const float* ewS = (const float*)d_in[2];
  const int* eiD = (const int*)d_in[3];
  const float* ewD = (const float*)d_in[4];
  const float* W1 = (const float*)d_in[5];
  const float* b1 = (const float*)d_in[6];
  const float* W2 = (const float*)d_in[7];
  const float* b2 = (const float*)d_in[8];
  const float* Ws = (const float*)d_in[9];
  const float* bs = (const float*)d_in[10];
  const float* Wd = (const float*)d_in[11];
  const float* bd = (const float*)d_in[12];
  const float* Wf = (const float*)d_in[13];
  const float* bf_ = (const float*)d_in[14];
  float* out = (float*)d_out;

  char* p = (char*)d_ws;
  auto alloc = [&](size_t n) -> char* { char* r = p; p += (n + 255) & ~(size_t)255; return r; };

  u16* xb    = (u16*)alloc((size_t)MPAD * K1P * 2);
  u16* w12t  = (u16*)alloc((size_t)NW * K1P * 2);
  u16* h12   = (u16*)alloc((size_t)N_NODES * NW * 2);
  u16* xsd   = (u16*)alloc((size_t)2 * MPAD * H_DIM * 2);
  u16* hsb   = (u16*)alloc((size_t)N_NODES * O_DIM * 2);
  u16* hdb   = (u16*)alloc((size_t)N_NODES * O_DIM * 2);
  u16* xcat  = (u16*)alloc((size_t)MPAD * H_DIM * 2);
  u16* wst   = (u16*)alloc((size_t)O_DIM * H_DIM * 2);
  u16* wdt   = (u16*)alloc((size_t)O_DIM * H_DIM * 2);
  u16* wft   = (u16*)alloc((size_t)O_DIM * H_DIM * 2);
  float* degS = (float*)alloc((size_t)N_NODES * 4);
  float* degD = (float*)alloc((size_t)N_NODES * 4);
  float* dinvS = (float*)alloc((size_t)N_NODES * 4);
  float* dinvD = (float*)alloc((size_t)N_NODES * 4);
  int* cntS = (int*)alloc((size_t)N_NODES * 4);
  int* cntD = (int*)alloc((size_t)N_NODES * 4);
  int* offS = (int*)alloc((size_t)(N_NODES + 1) * 4);
  int* offD = (int*)alloc((size_t)(N_NODES + 1) * 4);
  int* eposS = (int*)alloc((size_t)E_EDGES * 4);
  int* eposD = (int*)alloc((size_t)E_EDGES * 4);
  int* ssrcS = (int*)alloc((size_t)E_EDGES * 4);
  int* ssrcD = (int*)alloc((size_t)E_EDGES * 4);
  float* snrmS = (float*)alloc((size_t)E_EDGES * 4);
  float* snrmD = (float*)alloc((size_t)E_EDGES * 4);

  const int gN = (N_NODES + 255) / 256;     // 79

  deg_init_k<<<gN, 256, 0, stream>>>(degS, degD, cntS, cntD);

  // fused convs + deg_accum (independent work, one dispatch)
  pre_k<<<MPAD + 752 + 96 + NB_EDGE, 256, 0, stream>>>(
      x, xb, W1, W2, w12t, Ws, Wd, Wf, wst, wdt, wft,
      eiS, ewS, eiD, ewD, degS, degD, cntS, cntD, eposS, eposD);

  scan_k<<<2, 1024, (size_t)(1024 + N_NODES) * 4, stream>>>(cntS, offS, degS, dinvS,
                                                            cntD, offD, degD, dinvD);

  // big GEMM + edge scatter fused (scatter hides under the GEMM)
  gemm_sc_k<<<NB_GEMM + NB_EDGE, 256, 0, stream>>>(
      xb, w12t, h12,
      eiS, ewS, dinvS, offS, eposS, ssrcS, snrmS,
      eiD, ewD, dinvD, offD, eposD, ssrcD, snrmD);

  agg1_k<<<dim3(MPAD / 4, 2), 256, 0, stream>>>(h12, offS, ssrcS, snrmS, dinvS, b1,
                                                offD, ssrcD, snrmD, dinvD, b2, xsd);

  // hsb = xs @ Ws^T and hdb = xd @ Wd^T in one dispatch (628 blocks)
  gemm_pair_k<<<dim3(2, 157, 2), 256, 0, stream>>>(xsd, wst, hsb,
                                                   xsd + (size_t)MPAD * H_DIM, wdt, hdb);

  agg2_k<<<dim3(MPAD / 4, 2), 256, 0, stream>>>(hsb, hdb, offS, ssrcS, snrmS, dinvS, bs,
                                                offD, ssrcD, snrmD, dinvD, bd, out, xcat);

  // fused = xcat @ wft^T + bf  -> d_out[2*N*O ..]
  gemm_f_k<<<dim3(2, 157), 256, 0, stream>>>(xcat, wft, out + (size_t)2 * N_NODES * O_DIM, bf_);
}